// Round 5
// baseline (577.410 us; speedup 1.0000x reference)
//
#include <hip/hip_runtime.h>
#include <hip/hip_bf16.h>

// Problem constants
#define SEQ 2048
#define HD  128
#define NH  32
#define NKV 8
#define MODEL 4096   // NH*HD
#define KVDIM 1024   // NKV*HD
#define QKVN 6144    // fused Q+K+V output width

typedef __attribute__((ext_vector_type(8))) short short8;
typedef __attribute__((ext_vector_type(4))) short short4v;
typedef __attribute__((ext_vector_type(4))) float float4v;

#define MFMA16(a, b, c) __builtin_amdgcn_mfma_f32_16x16x32_bf16(a, b, c, 0, 0, 0)

__device__ __forceinline__ short f2bf(float x) {
  unsigned u = __builtin_bit_cast(unsigned, x);
  u += 0x7fffu + ((u >> 16) & 1u);   // RNE, fine for finite values
  return (short)(u >> 16);
}
__device__ __forceinline__ float bf2f(short s) {
  unsigned u = ((unsigned)(unsigned short)s) << 16;
  return __builtin_bit_cast(float, u);
}

// async global -> LDS, 16 B per lane; lds dest is wave-uniform base + lane*16
__device__ __forceinline__ void async_copy16(const void* g, void* l) {
  __builtin_amdgcn_global_load_lds((const __attribute__((address_space(1))) void*)g,
                                   (__attribute__((address_space(3))) void*)l, 16, 0, 0);
}

// ---------------------------------------------------------------------------
// Fused fp32 -> bf16 cast of all 5 tensors in ONE launch.
// The bf16 destinations are contiguous in workspace (alloc order wq,wk,wv,wo,h;
// every region size is a multiple of 256 B), and every region elem count is a
// multiple of 1024, so blockIdx ranges map 1:1 to regions.
//   blocks: Wq [0,16384) | Wk [16384,20480) | Wv [20480,24576)
//           | Wo [24576,40960) | hidden [40960,49152)
// ---------------------------------------------------------------------------
__global__ __launch_bounds__(256) void cast_fused(const float* __restrict__ wq,
                                                  const float* __restrict__ wk,
                                                  const float* __restrict__ wv,
                                                  const float* __restrict__ wo,
                                                  const float* __restrict__ hid,
                                                  short* __restrict__ dst) {
  int b = blockIdx.x;
  const float* src;
  int rbase, lblk;
  if (b < 16384)      { src = wq;  rbase = 0;     lblk = b; }
  else if (b < 20480) { src = wk;  rbase = 16384; lblk = b - 16384; }
  else if (b < 24576) { src = wv;  rbase = 20480; lblk = b - 20480; }
  else if (b < 40960) { src = wo;  rbase = 24576; lblk = b - 24576; }
  else                { src = hid; rbase = 40960; lblk = b - 40960; }
  size_t li = (size_t)lblk * 1024 + threadIdx.x * 4;
  float4v v = *(const float4v*)(src + li);
  short4v o;
  o[0] = f2bf(v[0]); o[1] = f2bf(v[1]); o[2] = f2bf(v[2]); o[3] = f2bf(v[3]);
  *(short4v*)(dst + (size_t)rbase * 1024 + li) = o;
}

__device__ __forceinline__ void store_out(float* C, size_t idx, float v) { C[idx] = v; }
__device__ __forceinline__ void store_out(short* C, size_t idx, float v) { C[idx] = f2bf(v); }

// ---------------------------------------------------------------------------
// 256 x (NI*64) 4-phase NT bf16 GEMM (T2 swizzle + counted vmcnt + T5).
// Best measured QKV variant (R2: 116.7 us, MfmaUtil 37%).  512 threads =
// 8 waves (2M x 4N), wave tile 128 x NI*16, BK=64, LDS double-buffered.
// QKV: NI=3 -> 256x192 tile, grid 8*32 = 256 blocks (1/CU, balanced).
// K-tile = 4 phases over mi-pairs; B frags read once at p0 and held.
// ---------------------------------------------------------------------------
template <int NI, typename OUT>
__global__ __launch_bounds__(512, 2) void gemm256v(const short* __restrict__ A,
                                                   const short* __restrict__ B,
                                                   OUT* __restrict__ C,
                                                   int M, int N, int K) {
  constexpr int BN = NI * 64;
  __shared__ __align__(16) short As[2][256 * 64];   // 64 KB
  __shared__ __align__(16) short Bs[2][BN * 64];    // 48 KB (NI=3)
  const int tid = threadIdx.x;
  const int lane = tid & 63, w = tid >> 6;
  const int col = lane & 15, quad = lane >> 4;
  const int wm = w >> 2, wn = w & 3;

  // XCD-aware bijective swizzle (nwg = 256, % 8 == 0)
  const int nbx = N / BN;
  int bid = blockIdx.x, nwg = gridDim.x;
  int swz = (nwg & 7) ? bid : ((bid & 7) * (nwg >> 3) + (bid >> 3));
  const int m0 = (swz / nbx) << 8;
  const int n0 = (swz % nbx) * BN;

  // staging source (swizzle folded into the GLOBAL chunk index; LDS linear)
  const int srow = tid >> 3;                       // row within 64-row chunk
  const int schunk = (tid & 7) ^ (srow & 7);       // source 16B-chunk within row
  const short* pA = A + (size_t)(m0 + srow) * K + schunk * 8;
  const short* pB = B + (size_t)(n0 + srow) * K + schunk * 8;
  const int ldst = tid * 8;                        // linear LDS dest (shorts)

  // fragment-read constants: offset = row*64 + ((ks*32 + quad*8) ^ ((row&7)<<3))
  const int sw = (col & 7) << 3;
  const int kof0 = (quad * 8) ^ sw;
  const int kof1 = (32 + quad * 8) ^ sw;
  const int ra = wm * 128, rb = wn * (NI * 16);

  float4v acc[8][NI] = {};
  const int iters = K >> 6;

#define SA(buf, rA, kt) async_copy16(pA + (size_t)(rA) * K + (kt), &As[buf][(rA) * 64 + ldst])
#define SB_(buf, rB, kt) async_copy16(pB + (size_t)(rB) * K + (kt), &Bs[buf][(rB) * 64 + ldst])

  // prologue: tile 0, issue order A0,A2,B0,B1,(B2),A1,A3
  SA(0, 0, 0);  SA(0, 128, 0);
  SB_(0, 0, 0); SB_(0, 64, 0);
  if constexpr (NI == 3) SB_(0, 128, 0);
  SA(0, 64, 0); SA(0, 192, 0);
  asm volatile("s_waitcnt vmcnt(2)" ::: "memory");   // all but A1,A3 resident
  __builtin_amdgcn_s_barrier();

  for (int t = 0; t < iters; ++t) {
    const int cb = t & 1, nb = cb ^ 1;
    const int kt = (t + 1) << 6;
    const bool pf = (t + 1 < iters);
    const short* a_ = As[cb];
    const short* b_ = Bs[cb];
    short8 bf[NI][2];   // held across all 4 phases
    short8 af[2][2];

    // ---- phase 0: mi {0,1}  (+ load all B fragments) ----
#pragma unroll
    for (int j = 0; j < 2; ++j) {
      const short* rp = a_ + (ra + j * 16 + col) * 64;
      af[j][0] = *(const short8*)(rp + kof0);
      af[j][1] = *(const short8*)(rp + kof1);
    }
#pragma unroll
    for (int ni = 0; ni < NI; ++ni) {
      const short* rp = b_ + (rb + ni * 16 + col) * 64;
      bf[ni][0] = *(const short8*)(rp + kof0);
      bf[ni][1] = *(const short8*)(rp + kof1);
    }
    if (pf) { SA(nb, 0, kt); SA(nb, 128, kt); }
    __builtin_amdgcn_s_barrier();
    asm volatile("s_waitcnt lgkmcnt(0)" ::: "memory");
    __builtin_amdgcn_sched_barrier(0);
    __builtin_amdgcn_s_setprio(1);
#pragma unroll
    for (int j = 0; j < 2; ++j)
#pragma unroll
      for (int ni = 0; ni < NI; ++ni) {
        acc[j][ni] = MFMA16(af[j][0], bf[ni][0], acc[j][ni]);
        acc[j][ni] = MFMA16(af[j][1], bf[ni][1], acc[j][ni]);
      }
    __builtin_amdgcn_s_setprio(0);
    __builtin_amdgcn_s_barrier();

    // ---- phase 1: mi {2,3} ----
#pragma unroll
    for (int j = 0; j < 2; ++j) {
      const short* rp = a_ + (ra + (2 + j) * 16 + col) * 64;
      af[j][0] = *(const short8*)(rp + kof0);
      af[j][1] = *(const short8*)(rp + kof1);
    }
    if (pf) { SB_(nb, 0, kt); SB_(nb, 64, kt); }
    __builtin_amdgcn_s_barrier();
    asm volatile("s_waitcnt lgkmcnt(0)" ::: "memory");
    __builtin_amdgcn_sched_barrier(0);
    __builtin_amdgcn_s_setprio(1);
#pragma unroll
    for (int j = 0; j < 2; ++j)
#pragma unroll
      for (int ni = 0; ni < NI; ++ni) {
        acc[2 + j][ni] = MFMA16(af[j][0], bf[ni][0], acc[2 + j][ni]);
        acc[2 + j][ni] = MFMA16(af[j][1], bf[ni][1], acc[2 + j][ni]);
      }
    __builtin_amdgcn_s_setprio(0);
    if (pf) asm volatile("s_waitcnt vmcnt(4)" ::: "memory");  // A1,A3 of t done
    else    asm volatile("s_waitcnt vmcnt(0)" ::: "memory");  // final drain
    __builtin_amdgcn_s_barrier();

    // ---- phase 2: mi {4,5} ----
#pragma unroll
    for (int j = 0; j < 2; ++j) {
      const short* rp = a_ + (ra + (4 + j) * 16 + col) * 64;
      af[j][0] = *(const short8*)(rp + kof0);
      af[j][1] = *(const short8*)(rp + kof1);
    }
    if (pf) { if constexpr (NI == 3) SB_(nb, 128, kt); }
    __builtin_amdgcn_s_barrier();
    asm volatile("s_waitcnt lgkmcnt(0)" ::: "memory");
    __builtin_amdgcn_sched_barrier(0);
    __builtin_amdgcn_s_setprio(1);
#pragma unroll
    for (int j = 0; j < 2; ++j)
#pragma unroll
      for (int ni = 0; ni < NI; ++ni) {
        acc[4 + j][ni] = MFMA16(af[j][0], bf[ni][0], acc[4 + j][ni]);
        acc[4 + j][ni] = MFMA16(af[j][1], bf[ni][1], acc[4 + j][ni]);
      }
    __builtin_amdgcn_s_setprio(0);
    __builtin_amdgcn_s_barrier();

    // ---- phase 3: mi {6,7} ----
#pragma unroll
    for (int j = 0; j < 2; ++j) {
      const short* rp = a_ + (ra + (6 + j) * 16 + col) * 64;
      af[j][0] = *(const short8*)(rp + kof0);
      af[j][1] = *(const short8*)(rp + kof1);
    }
    if (pf) { SA(nb, 64, kt); SA(nb, 192, kt); }
    __builtin_amdgcn_s_barrier();
    asm volatile("s_waitcnt lgkmcnt(0)" ::: "memory");
    __builtin_amdgcn_sched_barrier(0);
    __builtin_amdgcn_s_setprio(1);
#pragma unroll
    for (int j = 0; j < 2; ++j)
#pragma unroll
      for (int ni = 0; ni < NI; ++ni) {
        acc[6 + j][ni] = MFMA16(af[j][0], bf[ni][0], acc[6 + j][ni]);
        acc[6 + j][ni] = MFMA16(af[j][1], bf[ni][1], acc[6 + j][ni]);
      }
    __builtin_amdgcn_s_setprio(0);
    if (pf) asm volatile("s_waitcnt vmcnt(2)" ::: "memory");  // t+1 p0 set ready
    __builtin_amdgcn_s_barrier();
  }
#undef SA
#undef SB_

  // epilogue: verified C-layout (row = quad*4+r within fragment, col = lane&15)
#pragma unroll
  for (int mi = 0; mi < 8; ++mi)
#pragma unroll
    for (int ni = 0; ni < NI; ++ni)
#pragma unroll
      for (int r = 0; r < 4; ++r) {
        int row = m0 + ra + mi * 16 + quad * 4 + r;
        int cc  = n0 + rb + ni * 16 + col;
        store_out(C, (size_t)row * N + cc, acc[mi][ni][r]);
      }
}

// ---------------------------------------------------------------------------
// NT bf16 GEMM, double-buffered LDS pipeline: C[M,N] = A[M,K] * B[N,K]^T
// 128x128 tile, BK=32, 256 threads.  Proven for the Wo projection
// (512 tiles -> 2 blocks/CU, balanced).
// ---------------------------------------------------------------------------
#define BM 128
#define BN 128
#define BK 32

template <typename OUT>
__global__ __launch_bounds__(256) void gemm_nt(const short* __restrict__ A,
                                               const short* __restrict__ B,
                                               OUT* __restrict__ C,
                                               int M, int N, int K) {
  __shared__ __align__(16) short As[2][BM * BK];   // 2 x 8 KB
  __shared__ __align__(16) short Bs[2][BN * BK];   // 2 x 8 KB
  int t = threadIdx.x;
  int w = t >> 6, lane = t & 63;
  int col = lane & 15, quad = lane >> 4;
  int m0 = blockIdx.y * BM, n0 = blockIdx.x * BN;
  int wr = (w >> 1) * 64, wc = (w & 1) * 64;

  int srow   = lane >> 2;
  int schunk = (lane & 3) ^ ((lane >> 3) & 3);
  const short* Ag0 = A + (size_t)(m0 + w * 32 + srow) * K + schunk * 8;
  const short* Ag1 = Ag0 + (size_t)16 * K;
  const short* Bg0 = B + (size_t)(n0 + w * 32 + srow) * K + schunk * 8;
  const short* Bg1 = Bg0 + (size_t)16 * K;
  const int wofs0 = (w * 32) * BK;
  const int wofs1 = (w * 32 + 16) * BK;

  int aswz = (quad ^ ((col >> 1) & 3)) * 8;

  float4v acc[4][4] = {};

  async_copy16(Ag0, &As[0][wofs0]);
  async_copy16(Ag1, &As[0][wofs1]);
  async_copy16(Bg0, &Bs[0][wofs0]);
  async_copy16(Bg1, &Bs[0][wofs1]);
  __syncthreads();

  const int iters = K / BK;
  for (int it = 0; it < iters; it++) {
    const int cb = it & 1, nb = cb ^ 1;
    if (it + 1 < iters) {
      const int k0 = (it + 1) * BK;
      async_copy16(Ag0 + k0, &As[nb][wofs0]);
      async_copy16(Ag1 + k0, &As[nb][wofs1]);
      async_copy16(Bg0 + k0, &Bs[nb][wofs0]);
      async_copy16(Bg1 + k0, &Bs[nb][wofs1]);
    }
    short8 af[4], bfr[4];
#pragma unroll
    for (int i = 0; i < 4; i++)
      af[i] = *(const short8*)&As[cb][(wr + i * 16 + col) * BK + aswz];
#pragma unroll
    for (int i = 0; i < 4; i++)
      bfr[i] = *(const short8*)&Bs[cb][(wc + i * 16 + col) * BK + aswz];
#pragma unroll
    for (int mi = 0; mi < 4; mi++)
#pragma unroll
      for (int ni = 0; ni < 4; ni++)
        acc[mi][ni] = MFMA16(af[mi], bfr[ni], acc[mi][ni]);
    __syncthreads();
  }

#pragma unroll
  for (int mi = 0; mi < 4; mi++)
#pragma unroll
    for (int ni = 0; ni < 4; ni++)
#pragma unroll
      for (int r = 0; r < 4; r++) {
        int row = m0 + wr + mi * 16 + quad * 4 + r;
        int cc  = n0 + wc + ni * 16 + col;
        store_out(C, (size_t)row * N + cc, acc[mi][ni][r]);
      }
}

// ---------------------------------------------------------------------------
// RoPE + layout change.  blockIdx.x = s, blockIdx.y = head (0..39: 0-31 Q, 32-39 K)
// ---------------------------------------------------------------------------
__global__ __launch_bounds__(128) void rope_kernel(const short* __restrict__ qkv,
                                                   const float* __restrict__ cosp,
                                                   const float* __restrict__ sinp,
                                                   short* __restrict__ qb,
                                                   short* __restrict__ kb) {
  int s = blockIdx.x, head = blockIdx.y, d = threadIdx.x;
  float c  = cosp[s * HD + d];
  float sn = sinp[s * HD + d];
  if (head < NH) {
    const short* base = qkv + (size_t)s * QKVN + head * HD;
    float x = bf2f(base[d]);
    float rot = (d < 64) ? -bf2f(base[d + 64]) : bf2f(base[d - 64]);
    qb[((size_t)(head * SEQ + s)) * HD + d] = f2bf((x * c + rot * sn) * 0.08838834764831845f);
  } else {
    int hk = head - NH;
    const short* base = qkv + (size_t)s * QKVN + MODEL + hk * HD;
    float x = bf2f(base[d]);
    float rot = (d < 64) ? -bf2f(base[d + 64]) : bf2f(base[d - 64]);
    kb[((size_t)(hk * SEQ + s)) * HD + d] = f2bf(x * c + rot * sn);
  }
}

// ---------------------------------------------------------------------------
// V transpose (pure bf16 permute): qkv_bf[s][5120 + kv*128 + d] -> v_t[kv][d][s]
// ---------------------------------------------------------------------------
__global__ __launch_bounds__(256) void vtrans_kernel(const short* __restrict__ qkv,
                                                     short* __restrict__ vt) {
  __shared__ short tile[32][34];
  int kv = blockIdx.z;
  int d0 = blockIdx.x * 32, s0 = blockIdx.y * 32;
  int tx = threadIdx.x, ty = threadIdx.y;
#pragma unroll
  for (int j = 0; j < 32; j += 8)
    tile[ty + j][tx] = qkv[(size_t)(s0 + ty + j) * QKVN + MODEL + KVDIM + kv * HD + d0 + tx];
  __syncthreads();
#pragma unroll
  for (int j = 0; j < 32; j += 8)
    vt[((size_t)(kv * HD + d0 + ty + j)) * SEQ + s0 + tx] = tile[tx][ty + j];
}

// ---------------------------------------------------------------------------
// Flash attention v5: barrier-free, LDS-free K/V (L2-direct reads).
// K (512 KB/head) and V^T are L2-hot (shared by 4 q-blocks/head and 4 waves/
// block), so the v4 global->LDS->reg staging round-trip + per-tile
// __syncthreads was pure overhead (Common-mistake #7 / m169).  Now:
//   - K fragments and V^T fragments are loaded straight from global per tile
//     (16 x b128 per wave; 16 rows x 64 B segments, L2-friendly).
//   - V loads issue BEFORE the QK^T MFMAs -> ~400 cyc latency cover.
//   - Only P goes through LDS, in a per-wave region -> no barrier anywhere;
//     wave-local lgkmcnt(0) orders P write->read (DS is in-order per wave).
//   - Each wave loops only over ITS causal range (q0w+31 keys), not the
//     block maximum.
//   - T5 setprio around both MFMA clusters (m191: attn-positive regime =
//     desynced waves, which barrier-free gives us).
// Same math, same summation order as v4 -> bit-identical output.
// ---------------------------------------------------------------------------
#define PLD 40    // P LDS stride in shorts (32 + 8 pad)

__global__ __launch_bounds__(256, 2) void flash_attn(const short* __restrict__ qb_,
                                                     const short* __restrict__ kb,
                                                     const short* __restrict__ vt,
                                                     short* __restrict__ attn) {
  __shared__ __align__(16) short Ps[4][32 * PLD];   // 10240 B, per-wave regions
  const int tid = threadIdx.x;
  const int w = tid >> 6, lane = tid & 63;
  const int col = lane & 15, quad = lane >> 4;
  const int h = blockIdx.x;
  const int kv = h >> 2;
  const int yp = (blockIdx.y < 8) ? (15 - (int)blockIdx.y) : ((int)blockIdx.y - 8);
  const int qB0 = yp * 128;                  // long blocks dispatch first
  const int q0w = qB0 + w * 32;
  const int wtiles = (q0w + 31) >> 5;        // this wave's last causal tile

  short8 ones;
#pragma unroll
  for (int i = 0; i < 8; i++) ones[i] = (short)0x3F80;   // bf16 1.0

  // Q fragments (B-operand): 32 rows x 128 d, pre-scaled by 1/sqrt(D)
  short8 qf[2][4];
  const short* qbase = qb_ + ((size_t)(h * SEQ + q0w + col)) * HD;
#pragma unroll
  for (int rt = 0; rt < 2; rt++)
#pragma unroll
    for (int ks = 0; ks < 4; ks++)
      qf[rt][ks] = *(const short8*)(qbase + rt * 16 * HD + ks * 32 + quad * 8);

  float4v o[2][8] = {};   // O^T: [rt][nc], lane holds d=nc*16+quad*4+r, qrow=rt*16+col
  float4v la[2] = {};     // l[qrow=col] via ones-MFMA (all 4 regs equal)

  const short* kgbase = kb + ((size_t)kv * SEQ) * HD;
  const short* vgbase = vt + ((size_t)kv * HD) * SEQ;
  short* pw = Ps[w];

  for (int kt = 0; kt <= wtiles; kt++) {
    const int key0 = kt * 32;
    // --- V^T fragments first (consumed after softmax -> long latency cover) ---
    short8 vb[8];
#pragma unroll
    for (int nc = 0; nc < 8; nc++)
      vb[nc] = *(const short8*)(vgbase + (size_t)(nc * 16 + col) * SEQ + key0 + quad * 8);
    // --- K fragments: rows key0+col (kt2=0) and key0+16+col (kt2=1) ---
    short8 kf0[4], kf1[4];
    const short* kg = kgbase + (size_t)(key0 + col) * HD + quad * 8;
#pragma unroll
    for (int ks = 0; ks < 4; ks++) {
      kf0[ks] = *(const short8*)(kg + ks * 32);
      kf1[ks] = *(const short8*)(kg + 16 * HD + ks * 32);
    }
    // --- S^T = K.Q^T : [kt2][rt], keys kt2*16+quad*4+r, qrow rt*16+col ---
    float4v sct[2][2] = {};
    __builtin_amdgcn_s_setprio(1);
#pragma unroll
    for (int ks = 0; ks < 4; ks++) {
      sct[0][0] = MFMA16(kf0[ks], qf[0][ks], sct[0][0]);
      sct[0][1] = MFMA16(kf0[ks], qf[1][ks], sct[0][1]);
      sct[1][0] = MFMA16(kf1[ks], qf[0][ks], sct[1][0]);
      sct[1][1] = MFMA16(kf1[ks], qf[1][ks], sct[1][1]);
    }
    __builtin_amdgcn_s_setprio(0);
    // --- mask + exp + packed b64 store of P^T (no max, no shuffles) ---
#pragma unroll
    for (int rt = 0; rt < 2; rt++) {
      int qrow = q0w + rt * 16 + col;
#pragma unroll
      for (int kt2 = 0; kt2 < 2; kt2++) {
        int keyb = key0 + kt2 * 16 + quad * 4;
        short4v p;
#pragma unroll
        for (int r = 0; r < 4; r++) {
          float s = sct[kt2][rt][r];
          if (keyb + r > qrow) s = -INFINITY;
          p[r] = f2bf(__expf(s));
        }
        *(short4v*)&pw[(rt * 16 + col) * PLD + kt2 * 16 + quad * 4] = p;
      }
    }
    asm volatile("s_waitcnt lgkmcnt(0)" ::: "memory");
    // --- P^T B-frags, then O^T += V^T . P^T ;  l += ones . P^T ---
    short8 pf0 = *(const short8*)&pw[col * PLD + quad * 8];
    short8 pf1 = *(const short8*)&pw[(16 + col) * PLD + quad * 8];
    __builtin_amdgcn_s_setprio(1);
    la[0] = MFMA16(ones, pf0, la[0]);
    la[1] = MFMA16(ones, pf1, la[1]);
#pragma unroll
    for (int nc = 0; nc < 8; nc++) {
      o[0][nc] = MFMA16(vb[nc], pf0, o[0][nc]);
      o[1][nc] = MFMA16(vb[nc], pf1, o[1][nc]);
    }
    __builtin_amdgcn_s_setprio(0);
  }

  // epilogue: lane's qrow is fixed (= rt*16+col) -> one reciprocal per rt,
  // 4 consecutive d per packed 8-B store.
#pragma unroll
  for (int rt = 0; rt < 2; rt++) {
    float inv = 1.0f / la[rt][0];
    size_t rowbase = (size_t)(q0w + rt * 16 + col) * MODEL + h * HD + quad * 4;
#pragma unroll
    for (int nc = 0; nc < 8; nc++) {
      short4v ov;
#pragma unroll
      for (int r = 0; r < 4; r++) ov[r] = f2bf(o[rt][nc][r] * inv);
      *(short4v*)(attn + rowbase + nc * 16) = ov;
    }
  }
}

// ---------------------------------------------------------------------------
extern "C" void kernel_launch(void* const* d_in, const int* in_sizes, int n_in,
                              void* d_out, int out_size, void* d_ws, size_t ws_size,
                              hipStream_t stream) {
  const float* hidden = (const float*)d_in[0];
  // d_in[1] = attention_mask (pure causal; implemented inline)
  const float* cosp = (const float*)d_in[2];
  const float* sinp = (const float*)d_in[3];
  const float* Wq   = (const float*)d_in[4];
  const float* Wk   = (const float*)d_in[5];
  const float* Wv   = (const float*)d_in[6];
  const float* Wo   = (const float*)d_in[7];

  char* ws = (char*)d_ws;
  size_t off = 0;
  auto alloc = [&](size_t bytes) {
    char* p = ws + off;
    off += (bytes + 255) & ~(size_t)255;
    return p;
  };
  // alloc order wq,wk,wv,wo,h is load-bearing: cast_fused assumes these 5
  // regions are contiguous in this order (all sizes are 256B multiples).
  short* wq_bf = (short*)alloc((size_t)MODEL * MODEL * 2);
  short* wk_bf = (short*)alloc((size_t)KVDIM * MODEL * 2);
  short* wv_bf = (short*)alloc((size_t)KVDIM * MODEL * 2);
  short* wo_bf = (short*)alloc((size_t)MODEL * MODEL * 2);
  short* h_bf  = (short*)alloc((size_t)SEQ * MODEL * 2);
  short* qkv_bf = (short*)alloc((size_t)SEQ * QKVN * 2);
  short* k_bf  = (short*)alloc((size_t)NKV * SEQ * HD * 2);
  short* v_t   = (short*)alloc((size_t)NKV * HD * SEQ * 2);
  short* attn_bf = (short*)alloc((size_t)SEQ * MODEL * 2);
  short* q_bf    = h_bf;             // overlay: h_bf dead after QKV GEMM

  // 1) single fused cast of all 5 fp32 tensors to bf16
  cast_fused<<<49152, 256, 0, stream>>>(Wq, Wk, Wv, Wo, hidden, wq_bf);

  // 2) fused QKV projection: 256x192 4-phase, 256 blocks (best measured: R2)
  gemm256v<3, short><<<dim3((SEQ / 256) * (QKVN / 192)), 512, 0, stream>>>(
      h_bf, wq_bf, qkv_bf, SEQ, QKVN, MODEL);

  // 3) RoPE + layout; 4) V transpose
  rope_kernel<<<dim3(SEQ, NH + NKV), 128, 0, stream>>>(qkv_bf, cosp, sinp, q_bf, k_bf);
  vtrans_kernel<<<dim3(HD / 32, SEQ / 32, NKV), dim3(32, 8), 0, stream>>>(qkv_bf, v_t);

  // 5) flash attention v5: barrier-free, K/V from L2
  flash_attn<<<dim3(NH, SEQ / 128), 256, 0, stream>>>(q_bf, k_bf, v_t, attn_bf);

  // 6) output projection straight into d_out (fp32): proven 128^2 kernel
  gemm_nt<float><<<dim3(MODEL / BN, SEQ / BM), 256, 0, stream>>>(
      attn_bf, wo_bf, (float*)d_out, SEQ, MODEL, MODEL);
}

// Round 7
// 529.775 us; speedup vs baseline: 1.0899x; 1.0899x over previous
//
#include <hip/hip_runtime.h>
#include <hip/hip_bf16.h>

// Problem constants
#define SEQ 2048
#define HD  128
#define NH  32
#define NKV 8
#define MODEL 4096   // NH*HD
#define KVDIM 1024   // NKV*HD
#define QKVN 6144    // fused Q+K+V output width

typedef __attribute__((ext_vector_type(8))) short short8;
typedef __attribute__((ext_vector_type(4))) short short4v;
typedef __attribute__((ext_vector_type(4))) float float4v;

#define MFMA16(a, b, c) __builtin_amdgcn_mfma_f32_16x16x32_bf16(a, b, c, 0, 0, 0)

__device__ __forceinline__ short f2bf(float x) {
  unsigned u = __builtin_bit_cast(unsigned, x);
  u += 0x7fffu + ((u >> 16) & 1u);   // RNE, fine for finite values
  return (short)(u >> 16);
}
__device__ __forceinline__ float bf2f(short s) {
  unsigned u = ((unsigned)(unsigned short)s) << 16;
  return __builtin_bit_cast(float, u);
}

// async global -> LDS, 16 B per lane; lds dest is wave-uniform base + lane*16
__device__ __forceinline__ void async_copy16(const void* g, void* l) {
  __builtin_amdgcn_global_load_lds((const __attribute__((address_space(1))) void*)g,
                                   (__attribute__((address_space(3))) void*)l, 16, 0, 0);
}

// ---------------------------------------------------------------------------
// Fused fp32 -> bf16 cast of all 5 tensors in ONE launch.
//   blocks: Wq [0,16384) | Wk [16384,20480) | Wv [20480,24576)
//           | Wo [24576,40960) | hidden [40960,49152)
// ---------------------------------------------------------------------------
__global__ __launch_bounds__(256) void cast_fused(const float* __restrict__ wq,
                                                  const float* __restrict__ wk,
                                                  const float* __restrict__ wv,
                                                  const float* __restrict__ wo,
                                                  const float* __restrict__ hid,
                                                  short* __restrict__ dst) {
  int b = blockIdx.x;
  const float* src;
  int rbase, lblk;
  if (b < 16384)      { src = wq;  rbase = 0;     lblk = b; }
  else if (b < 20480) { src = wk;  rbase = 16384; lblk = b - 16384; }
  else if (b < 24576) { src = wv;  rbase = 20480; lblk = b - 20480; }
  else if (b < 40960) { src = wo;  rbase = 24576; lblk = b - 24576; }
  else                { src = hid; rbase = 40960; lblk = b - 40960; }
  size_t li = (size_t)lblk * 1024 + threadIdx.x * 4;
  float4v v = *(const float4v*)(src + li);
  short4v o;
  o[0] = f2bf(v[0]); o[1] = f2bf(v[1]); o[2] = f2bf(v[2]); o[3] = f2bf(v[3]);
  *(short4v*)(dst + (size_t)rbase * 1024 + li) = o;
}

__device__ __forceinline__ void store_out(float* C, size_t idx, float v) { C[idx] = v; }
__device__ __forceinline__ void store_out(short* C, size_t idx, float v) { C[idx] = f2bf(v); }

// ---------------------------------------------------------------------------
// 256 x (NI*64) 4-phase NT bf16 GEMM (T2 swizzle + counted vmcnt + T5).
// Best measured QKV variant (R2: 116.7 us).  512 threads = 8 waves (2M x 4N),
// wave tile 128 x NI*16, BK=64, LDS double-buffered.
// QKV: NI=3 -> 256x192 tile, grid 8*32 = 256 blocks (1/CU, balanced).
// ---------------------------------------------------------------------------
template <int NI, typename OUT>
__global__ __launch_bounds__(512, 2) void gemm256v(const short* __restrict__ A,
                                                   const short* __restrict__ B,
                                                   OUT* __restrict__ C,
                                                   int M, int N, int K) {
  constexpr int BN = NI * 64;
  __shared__ __align__(16) short As[2][256 * 64];   // 64 KB
  __shared__ __align__(16) short Bs[2][BN * 64];    // 48 KB (NI=3)
  const int tid = threadIdx.x;
  const int lane = tid & 63, w = tid >> 6;
  const int col = lane & 15, quad = lane >> 4;
  const int wm = w >> 2, wn = w & 3;

  // XCD-aware bijective swizzle (nwg = 256, % 8 == 0)
  const int nbx = N / BN;
  int bid = blockIdx.x, nwg = gridDim.x;
  int swz = (nwg & 7) ? bid : ((bid & 7) * (nwg >> 3) + (bid >> 3));
  const int m0 = (swz / nbx) << 8;
  const int n0 = (swz % nbx) * BN;

  // staging source (swizzle folded into the GLOBAL chunk index; LDS linear)
  const int srow = tid >> 3;                       // row within 64-row chunk
  const int schunk = (tid & 7) ^ (srow & 7);       // source 16B-chunk within row
  const short* pA = A + (size_t)(m0 + srow) * K + schunk * 8;
  const short* pB = B + (size_t)(n0 + srow) * K + schunk * 8;
  const int ldst = tid * 8;                        // linear LDS dest (shorts)

  // fragment-read constants: offset = row*64 + ((ks*32 + quad*8) ^ ((row&7)<<3))
  const int sw = (col & 7) << 3;
  const int kof0 = (quad * 8) ^ sw;
  const int kof1 = (32 + quad * 8) ^ sw;
  const int ra = wm * 128, rb = wn * (NI * 16);

  float4v acc[8][NI] = {};
  const int iters = K >> 6;

#define SA(buf, rA, kt) async_copy16(pA + (size_t)(rA) * K + (kt), &As[buf][(rA) * 64 + ldst])
#define SB_(buf, rB, kt) async_copy16(pB + (size_t)(rB) * K + (kt), &Bs[buf][(rB) * 64 + ldst])

  // prologue: tile 0, issue order A0,A2,B0,B1,(B2),A1,A3
  SA(0, 0, 0);  SA(0, 128, 0);
  SB_(0, 0, 0); SB_(0, 64, 0);
  if constexpr (NI == 3) SB_(0, 128, 0);
  SA(0, 64, 0); SA(0, 192, 0);
  asm volatile("s_waitcnt vmcnt(2)" ::: "memory");   // all but A1,A3 resident
  __builtin_amdgcn_s_barrier();

  for (int t = 0; t < iters; ++t) {
    const int cb = t & 1, nb = cb ^ 1;
    const int kt = (t + 1) << 6;
    const bool pf = (t + 1 < iters);
    const short* a_ = As[cb];
    const short* b_ = Bs[cb];
    short8 bf[NI][2];   // held across all 4 phases
    short8 af[2][2];

    // ---- phase 0: mi {0,1}  (+ load all B fragments) ----
#pragma unroll
    for (int j = 0; j < 2; ++j) {
      const short* rp = a_ + (ra + j * 16 + col) * 64;
      af[j][0] = *(const short8*)(rp + kof0);
      af[j][1] = *(const short8*)(rp + kof1);
    }
#pragma unroll
    for (int ni = 0; ni < NI; ++ni) {
      const short* rp = b_ + (rb + ni * 16 + col) * 64;
      bf[ni][0] = *(const short8*)(rp + kof0);
      bf[ni][1] = *(const short8*)(rp + kof1);
    }
    if (pf) { SA(nb, 0, kt); SA(nb, 128, kt); }
    __builtin_amdgcn_s_barrier();
    asm volatile("s_waitcnt lgkmcnt(0)" ::: "memory");
    __builtin_amdgcn_sched_barrier(0);
    __builtin_amdgcn_s_setprio(1);
#pragma unroll
    for (int j = 0; j < 2; ++j)
#pragma unroll
      for (int ni = 0; ni < NI; ++ni) {
        acc[j][ni] = MFMA16(af[j][0], bf[ni][0], acc[j][ni]);
        acc[j][ni] = MFMA16(af[j][1], bf[ni][1], acc[j][ni]);
      }
    __builtin_amdgcn_s_setprio(0);
    __builtin_amdgcn_s_barrier();

    // ---- phase 1: mi {2,3} ----
#pragma unroll
    for (int j = 0; j < 2; ++j) {
      const short* rp = a_ + (ra + (2 + j) * 16 + col) * 64;
      af[j][0] = *(const short8*)(rp + kof0);
      af[j][1] = *(const short8*)(rp + kof1);
    }
    if (pf) { SB_(nb, 0, kt); SB_(nb, 64, kt); }
    __builtin_amdgcn_s_barrier();
    asm volatile("s_waitcnt lgkmcnt(0)" ::: "memory");
    __builtin_amdgcn_sched_barrier(0);
    __builtin_amdgcn_s_setprio(1);
#pragma unroll
    for (int j = 0; j < 2; ++j)
#pragma unroll
      for (int ni = 0; ni < NI; ++ni) {
        acc[2 + j][ni] = MFMA16(af[j][0], bf[ni][0], acc[2 + j][ni]);
        acc[2 + j][ni] = MFMA16(af[j][1], bf[ni][1], acc[2 + j][ni]);
      }
    __builtin_amdgcn_s_setprio(0);
    if (pf) asm volatile("s_waitcnt vmcnt(4)" ::: "memory");  // A1,A3 of t done
    else    asm volatile("s_waitcnt vmcnt(0)" ::: "memory");  // final drain
    __builtin_amdgcn_s_barrier();

    // ---- phase 2: mi {4,5} ----
#pragma unroll
    for (int j = 0; j < 2; ++j) {
      const short* rp = a_ + (ra + (4 + j) * 16 + col) * 64;
      af[j][0] = *(const short8*)(rp + kof0);
      af[j][1] = *(const short8*)(rp + kof1);
    }
    if (pf) { if constexpr (NI == 3) SB_(nb, 128, kt); }
    __builtin_amdgcn_s_barrier();
    asm volatile("s_waitcnt lgkmcnt(0)" ::: "memory");
    __builtin_amdgcn_sched_barrier(0);
    __builtin_amdgcn_s_setprio(1);
#pragma unroll
    for (int j = 0; j < 2; ++j)
#pragma unroll
      for (int ni = 0; ni < NI; ++ni) {
        acc[4 + j][ni] = MFMA16(af[j][0], bf[ni][0], acc[4 + j][ni]);
        acc[4 + j][ni] = MFMA16(af[j][1], bf[ni][1], acc[4 + j][ni]);
      }
    __builtin_amdgcn_s_setprio(0);
    __builtin_amdgcn_s_barrier();

    // ---- phase 3: mi {6,7} ----
#pragma unroll
    for (int j = 0; j < 2; ++j) {
      const short* rp = a_ + (ra + (6 + j) * 16 + col) * 64;
      af[j][0] = *(const short8*)(rp + kof0);
      af[j][1] = *(const short8*)(rp + kof1);
    }
    if (pf) { SA(nb, 64, kt); SA(nb, 192, kt); }
    __builtin_amdgcn_s_barrier();
    asm volatile("s_waitcnt lgkmcnt(0)" ::: "memory");
    __builtin_amdgcn_sched_barrier(0);
    __builtin_amdgcn_s_setprio(1);
#pragma unroll
    for (int j = 0; j < 2; ++j)
#pragma unroll
      for (int ni = 0; ni < NI; ++ni) {
        acc[6 + j][ni] = MFMA16(af[j][0], bf[ni][0], acc[6 + j][ni]);
        acc[6 + j][ni] = MFMA16(af[j][1], bf[ni][1], acc[6 + j][ni]);
      }
    __builtin_amdgcn_s_setprio(0);
    if (pf) asm volatile("s_waitcnt vmcnt(2)" ::: "memory");  // t+1 p0 set ready
    __builtin_amdgcn_s_barrier();
  }
#undef SA
#undef SB_

  // epilogue: verified C-layout (row = quad*4+r within fragment, col = lane&15)
#pragma unroll
  for (int mi = 0; mi < 8; ++mi)
#pragma unroll
    for (int ni = 0; ni < NI; ++ni)
#pragma unroll
      for (int r = 0; r < 4; ++r) {
        int row = m0 + ra + mi * 16 + quad * 4 + r;
        int cc  = n0 + rb + ni * 16 + col;
        store_out(C, (size_t)row * N + cc, acc[mi][ni][r]);
      }
}

// ---------------------------------------------------------------------------
// NT bf16 GEMM, double-buffered LDS pipeline: C[M,N] = A[M,K] * B[N,K]^T
// 128x128 tile, BK=32, 256 threads.  Proven for the Wo projection.
// ---------------------------------------------------------------------------
#define BM 128
#define BN 128
#define BK 32

template <typename OUT>
__global__ __launch_bounds__(256) void gemm_nt(const short* __restrict__ A,
                                               const short* __restrict__ B,
                                               OUT* __restrict__ C,
                                               int M, int N, int K) {
  __shared__ __align__(16) short As[2][BM * BK];   // 2 x 8 KB
  __shared__ __align__(16) short Bs[2][BN * BK];   // 2 x 8 KB
  int t = threadIdx.x;
  int w = t >> 6, lane = t & 63;
  int col = lane & 15, quad = lane >> 4;
  int m0 = blockIdx.y * BM, n0 = blockIdx.x * BN;
  int wr = (w >> 1) * 64, wc = (w & 1) * 64;

  int srow   = lane >> 2;
  int schunk = (lane & 3) ^ ((lane >> 3) & 3);
  const short* Ag0 = A + (size_t)(m0 + w * 32 + srow) * K + schunk * 8;
  const short* Ag1 = Ag0 + (size_t)16 * K;
  const short* Bg0 = B + (size_t)(n0 + w * 32 + srow) * K + schunk * 8;
  const short* Bg1 = Bg0 + (size_t)16 * K;
  const int wofs0 = (w * 32) * BK;
  const int wofs1 = (w * 32 + 16) * BK;

  int aswz = (quad ^ ((col >> 1) & 3)) * 8;

  float4v acc[4][4] = {};

  async_copy16(Ag0, &As[0][wofs0]);
  async_copy16(Ag1, &As[0][wofs1]);
  async_copy16(Bg0, &Bs[0][wofs0]);
  async_copy16(Bg1, &Bs[0][wofs1]);
  __syncthreads();

  const int iters = K / BK;
  for (int it = 0; it < iters; it++) {
    const int cb = it & 1, nb = cb ^ 1;
    if (it + 1 < iters) {
      const int k0 = (it + 1) * BK;
      async_copy16(Ag0 + k0, &As[nb][wofs0]);
      async_copy16(Ag1 + k0, &As[nb][wofs1]);
      async_copy16(Bg0 + k0, &Bs[nb][wofs0]);
      async_copy16(Bg1 + k0, &Bs[nb][wofs1]);
    }
    short8 af[4], bfr[4];
#pragma unroll
    for (int i = 0; i < 4; i++)
      af[i] = *(const short8*)&As[cb][(wr + i * 16 + col) * BK + aswz];
#pragma unroll
    for (int i = 0; i < 4; i++)
      bfr[i] = *(const short8*)&Bs[cb][(wc + i * 16 + col) * BK + aswz];
#pragma unroll
    for (int mi = 0; mi < 4; mi++)
#pragma unroll
      for (int ni = 0; ni < 4; ni++)
        acc[mi][ni] = MFMA16(af[mi], bfr[ni], acc[mi][ni]);
    __syncthreads();
  }

#pragma unroll
  for (int mi = 0; mi < 4; mi++)
#pragma unroll
    for (int ni = 0; ni < 4; ni++)
#pragma unroll
      for (int r = 0; r < 4; r++) {
        int row = m0 + wr + mi * 16 + quad * 4 + r;
        int cc  = n0 + wc + ni * 16 + col;
        store_out(C, (size_t)row * N + cc, acc[mi][ni][r]);
      }
}

// ---------------------------------------------------------------------------
// rope_fused: RoPE(Q), RoPE(K), and V-transpose in ONE vectorized launch.
// Replaces the scalar rope_kernel (81920 x 128thr, 2-B accesses) and
// vtrans_kernel (2-B accesses) -- G13: bf16 moved as short8 (16 B/lane).
// Uses cos[s][d] == cos[s][d+64] (emb = concat(freqs,freqs)), so one 32-B
// cos + 32-B sin load serves both halves:  lo' = lo*c - hi*sn ;
// hi' = hi*c + lo*sn.
// Sections by blockIdx.x (256 threads each):
//   [0,2048):    Q rope   h  = b>>6,        s0 = (b&63)*32
//   [2048,2560): K rope   hk = (b-2048)>>6, s0 = ((b-2048)&63)*32
//   [2560,3072): V trans  kv = (b-2560)>>6, s0 = ((b-2560)&63)*32
// Q/K: thread = (row = t>>3, i = t&7): lo at d=i*8, hi at d=i*8+64.
// V: LDS tile [32][137] (pad 9 shorts -> 2-way bank aliasing, free).
// ---------------------------------------------------------------------------
__global__ __launch_bounds__(256) void rope_fused(const short* __restrict__ qkv,
                                                  const float* __restrict__ cosp,
                                                  const float* __restrict__ sinp,
                                                  short* __restrict__ qb,
                                                  short* __restrict__ kb,
                                                  short* __restrict__ vt) {
  __shared__ short tile[32][137];
  const int b = blockIdx.x, t = threadIdx.x;

  if (b < 2560) {   // ---- Q / K RoPE ----
    const bool isq = b < 2048;
    const int bb = isq ? b : b - 2048;
    const int head = bb >> 6;
    const int s = ((bb & 63) << 5) + (t >> 3);
    const int d0 = (t & 7) * 8;
    const int cbase = s * HD + d0;
    float4v c0 = *(const float4v*)(cosp + cbase);
    float4v c1 = *(const float4v*)(cosp + cbase + 4);
    float4v s0v = *(const float4v*)(sinp + cbase);
    float4v s1v = *(const float4v*)(sinp + cbase + 4);
    const short* base = qkv + (size_t)s * QKVN + (isq ? head * HD : MODEL + head * HD) + d0;
    short8 lo = *(const short8*)(base);
    short8 hi = *(const short8*)(base + 64);
    const float scale = isq ? 0.08838834764831845f : 1.0f;
    short8 olo, ohi;
#pragma unroll
    for (int j = 0; j < 8; j++) {
      float c = (j < 4) ? c0[j] : c1[j - 4];
      float sn = (j < 4) ? s0v[j] : s1v[j - 4];
      float l = bf2f(lo[j]), h = bf2f(hi[j]);
      olo[j] = f2bf((l * c - h * sn) * scale);
      ohi[j] = f2bf((h * c + l * sn) * scale);
    }
    short* out = (isq ? qb : kb) + ((size_t)(head * SEQ + s)) * HD + d0;
    *(short8*)(out) = olo;
    *(short8*)(out + 64) = ohi;
  } else {          // ---- V transpose ----
    const int bb = b - 2560;
    const int kv = bb >> 6;
    const int s0 = (bb & 63) << 5;
    const int lrow = t >> 4, chunk = t & 15;          // 16 rows x 16 chunks
    const short* src = qkv + (size_t)(s0 + lrow) * QKVN + MODEL + KVDIM + kv * HD + chunk * 8;
#pragma unroll
    for (int rr = 0; rr < 2; rr++)
      *(short8*)&tile[lrow + rr * 16][chunk * 8] =
          *(const short8*)(src + (size_t)rr * 16 * QKVN);
    __syncthreads();
    const int sc = t & 3, d = t >> 2;                 // 4 s-chunks x 64 d
#pragma unroll
    for (int dd = 0; dd < 2; dd++) {
      short8 o;
#pragma unroll
      for (int j = 0; j < 8; j++) o[j] = tile[sc * 8 + j][d + dd * 64];
      *(short8*)(vt + ((size_t)(kv * HD + d + dd * 64)) * SEQ + s0 + sc * 8) = o;
    }
  }
}

// ---------------------------------------------------------------------------
// Flash attention v4 (reverted from v5): transposed-score formulation with
// double-buffered LDS K/V staging and per-tile prefetch -- the prefetch
// pipeline is what v5 lost (its L2-direct loads serialized each tile on a
// full L2 round-trip).  Measured good in R4's 518.7 us total.
// ---------------------------------------------------------------------------
#define FKT 32    // keys per tile
#define KLD 136   // K LDS stride in shorts (128 + 8 pad)
#define VLD 40    // V LDS stride in shorts (32 + 8 pad)
#define PLD 40    // P LDS stride in shorts

__global__ __launch_bounds__(256, 3) void flash_attn(const short* __restrict__ qb_,
                                                     const short* __restrict__ kb,
                                                     const short* __restrict__ vt,
                                                     short* __restrict__ attn) {
  __shared__ __align__(16) short Ks[2][FKT * KLD];   // 17408 B
  __shared__ __align__(16) short Vs[2][HD * VLD];    // 20480 B
  __shared__ __align__(16) short Ps[4][32 * PLD];    // 10240 B
  const int tid = threadIdx.x;
  const int w = tid >> 6, lane = tid & 63;
  const int col = lane & 15, quad = lane >> 4;
  const int h = blockIdx.x;
  const int kv = h >> 2;
  const int yp = (blockIdx.y < 8) ? (15 - (int)blockIdx.y) : ((int)blockIdx.y - 8);
  const int qB0 = yp * 128;                  // long blocks dispatch first
  const int q0w = qB0 + w * 32;
  const int ntiles = qB0 / FKT + 4;

  short8 ones;
#pragma unroll
  for (int i = 0; i < 8; i++) ones[i] = (short)0x3F80;   // bf16 1.0

  // Q fragments (B-operand): 32 rows x 128 d, pre-scaled by 1/sqrt(D)
  short8 qf[2][4];
  const short* qbase = qb_ + ((size_t)(h * SEQ + q0w + col)) * HD;
#pragma unroll
  for (int rt = 0; rt < 2; rt++)
#pragma unroll
    for (int ks = 0; ks < 4; ks++)
      qf[rt][ks] = *(const short8*)(qbase + rt * 16 * HD + ks * 32 + quad * 8);

  float4v o[2][8] = {};   // O^T: [rt][nc], lane holds d=nc*16+quad*4+r, qrow=rt*16+col
  float4v la[2] = {};     // l[qrow=col] via ones-MFMA (all 4 regs equal)

  // staging geometry
  const int kg_off = tid * 8;
  const int klds0  = (kg_off >> 7) * KLD + (kg_off & 127);
  const int vd     = tid >> 2;
  const int vkof   = (tid & 3) * 8;
  const size_t vrow0 = ((size_t)(kv * HD + vd)) * SEQ;
  const size_t vrow1 = ((size_t)(kv * HD + vd + 64)) * SEQ;
  const int vlds0 = vd * VLD + vkof;
  const short* kgbase = kb + ((size_t)kv * SEQ) * HD;

  short8 kr0, kr1, vr0, vr1;
  kr0 = *(const short8*)(kgbase + kg_off);
  kr1 = *(const short8*)(kgbase + 2048 + kg_off);
  vr0 = *(const short8*)(vt + vrow0 + vkof);
  vr1 = *(const short8*)(vt + vrow1 + vkof);
  *(short8*)&Ks[0][klds0]            = kr0;
  *(short8*)&Ks[0][klds0 + 16 * KLD] = kr1;
  *(short8*)&Vs[0][vlds0]            = vr0;
  *(short8*)&Vs[0][vlds0 + 64 * VLD] = vr1;
  __syncthreads();

  for (int kt = 0; kt < ntiles; kt++) {
    const int b = kt & 1;
    const int key0 = kt * FKT;
    if (kt + 1 < ntiles) {
      const int nk0 = key0 + FKT;
      const short* kg = kgbase + (size_t)nk0 * HD;
      kr0 = *(const short8*)(kg + kg_off);
      kr1 = *(const short8*)(kg + 2048 + kg_off);
      vr0 = *(const short8*)(vt + vrow0 + nk0 + vkof);
      vr1 = *(const short8*)(vt + vrow1 + nk0 + vkof);
    }
    if (key0 <= q0w + 31) {
      // --- S^T = K.Q^T : [kt2][rt], keys kt2*16+quad*4+r, qrow rt*16+col ---
      float4v sct[2][2] = {};
#pragma unroll
      for (int ks = 0; ks < 4; ks++) {
        short8 kf0 = *(const short8*)&Ks[b][col * KLD + ks * 32 + quad * 8];
        short8 kf1 = *(const short8*)&Ks[b][(16 + col) * KLD + ks * 32 + quad * 8];
        sct[0][0] = MFMA16(kf0, qf[0][ks], sct[0][0]);
        sct[0][1] = MFMA16(kf0, qf[1][ks], sct[0][1]);
        sct[1][0] = MFMA16(kf1, qf[0][ks], sct[1][0]);
        sct[1][1] = MFMA16(kf1, qf[1][ks], sct[1][1]);
      }
      // --- mask + exp + packed b64 store of P^T (no max, no shuffles) ---
      short* pw = Ps[w];
#pragma unroll
      for (int rt = 0; rt < 2; rt++) {
        int qrow = q0w + rt * 16 + col;
#pragma unroll
        for (int kt2 = 0; kt2 < 2; kt2++) {
          int keyb = key0 + kt2 * 16 + quad * 4;
          short4v p;
#pragma unroll
          for (int r = 0; r < 4; r++) {
            float s = sct[kt2][rt][r];
            if (keyb + r > qrow) s = -INFINITY;
            p[r] = f2bf(__expf(s));
          }
          *(short4v*)&pw[(rt * 16 + col) * PLD + kt2 * 16 + quad * 4] = p;
        }
      }
      asm volatile("s_waitcnt lgkmcnt(0)" ::: "memory");
      // --- P^T B-frags, then O^T += V^T . P^T ;  l += ones . P^T ---
      short8 pf0 = *(const short8*)&pw[col * PLD + quad * 8];
      short8 pf1 = *(const short8*)&pw[(16 + col) * PLD + quad * 8];
      la[0] = MFMA16(ones, pf0, la[0]);
      la[1] = MFMA16(ones, pf1, la[1]);
#pragma unroll
      for (int nc = 0; nc < 8; nc++) {
        short8 vb = *(const short8*)&Vs[b][(nc * 16 + col) * VLD + quad * 8];
        o[0][nc] = MFMA16(vb, pf0, o[0][nc]);
        o[1][nc] = MFMA16(vb, pf1, o[1][nc]);
      }
    }
    if (kt + 1 < ntiles) {
      const int nb = 1 - b;
      *(short8*)&Ks[nb][klds0]            = kr0;
      *(short8*)&Ks[nb][klds0 + 16 * KLD] = kr1;
      *(short8*)&Vs[nb][vlds0]            = vr0;
      *(short8*)&Vs[nb][vlds0 + 64 * VLD] = vr1;
    }
    __syncthreads();
  }

  // epilogue: lane's qrow is fixed (= rt*16+col) -> one reciprocal per rt,
  // 4 consecutive d per packed 8-B store.
#pragma unroll
  for (int rt = 0; rt < 2; rt++) {
    float inv = 1.0f / la[rt][0];
    size_t rowbase = (size_t)(q0w + rt * 16 + col) * MODEL + h * HD + quad * 4;
#pragma unroll
    for (int nc = 0; nc < 8; nc++) {
      short4v ov;
#pragma unroll
      for (int r = 0; r < 4; r++) ov[r] = f2bf(o[rt][nc][r] * inv);
      *(short4v*)(attn + rowbase + nc * 16) = ov;
    }
  }
}

// ---------------------------------------------------------------------------
extern "C" void kernel_launch(void* const* d_in, const int* in_sizes, int n_in,
                              void* d_out, int out_size, void* d_ws, size_t ws_size,
                              hipStream_t stream) {
  const float* hidden = (const float*)d_in[0];
  // d_in[1] = attention_mask (pure causal; implemented inline)
  const float* cosp = (const float*)d_in[2];
  const float* sinp = (const float*)d_in[3];
  const float* Wq   = (const float*)d_in[4];
  const float* Wk   = (const float*)d_in[5];
  const float* Wv   = (const float*)d_in[6];
  const float* Wo   = (const float*)d_in[7];

  char* ws = (char*)d_ws;
  size_t off = 0;
  auto alloc = [&](size_t bytes) {
    char* p = ws + off;
    off += (bytes + 255) & ~(size_t)255;
    return p;
  };
  // alloc order wq,wk,wv,wo,h is load-bearing: cast_fused assumes these 5
  // regions are contiguous in this order (all sizes are 256B multiples).
  short* wq_bf = (short*)alloc((size_t)MODEL * MODEL * 2);
  short* wk_bf = (short*)alloc((size_t)KVDIM * MODEL * 2);
  short* wv_bf = (short*)alloc((size_t)KVDIM * MODEL * 2);
  short* wo_bf = (short*)alloc((size_t)MODEL * MODEL * 2);
  short* h_bf  = (short*)alloc((size_t)SEQ * MODEL * 2);
  short* qkv_bf = (short*)alloc((size_t)SEQ * QKVN * 2);
  short* k_bf  = (short*)alloc((size_t)NKV * SEQ * HD * 2);
  short* v_t   = (short*)alloc((size_t)NKV * HD * SEQ * 2);
  short* attn_bf = (short*)alloc((size_t)SEQ * MODEL * 2);
  short* q_bf    = h_bf;             // overlay: h_bf dead after QKV GEMM

  // 1) single fused cast of all 5 fp32 tensors to bf16
  cast_fused<<<49152, 256, 0, stream>>>(Wq, Wk, Wv, Wo, hidden, wq_bf);

  // 2) fused QKV projection: 256x192 4-phase, 256 blocks (best measured: R2)
  gemm256v<3, short><<<dim3((SEQ / 256) * (QKVN / 192)), 512, 0, stream>>>(
      h_bf, wq_bf, qkv_bf, SEQ, QKVN, MODEL);

  // 3) RoPE(Q) + RoPE(K) + V-transpose in one vectorized launch
  rope_fused<<<3072, 256, 0, stream>>>(qkv_bf, cosp, sinp, q_bf, k_bf, v_t);

  // 4) flash attention v4 (LDS-staged, prefetch-pipelined)
  flash_attn<<<dim3(NH, SEQ / 128), 256, 0, stream>>>(q_bf, k_bf, v_t, attn_bf);

  // 5) output projection straight into d_out (fp32): proven 128^2 kernel
  gemm_nt<float><<<dim3(MODEL / BN, SEQ / BM), 256, 0, stream>>>(
      attn_bf, wo_bf, (float*)d_out, SEQ, MODEL, MODEL);
}

// Round 8
// 500.341 us; speedup vs baseline: 1.1540x; 1.0588x over previous
//
#include <hip/hip_runtime.h>
#include <hip/hip_bf16.h>

// Problem constants
#define SEQ 2048
#define HD  128
#define NH  32
#define NKV 8
#define MODEL 4096   // NH*HD
#define KVDIM 1024   // NKV*HD
#define QKVN 6144    // fused Q+K+V output width

typedef __attribute__((ext_vector_type(8))) short short8;
typedef __attribute__((ext_vector_type(4))) short short4v;
typedef __attribute__((ext_vector_type(4))) float float4v;

#define MFMA16(a, b, c) __builtin_amdgcn_mfma_f32_16x16x32_bf16(a, b, c, 0, 0, 0)

__device__ __forceinline__ short f2bf(float x) {
  unsigned u = __builtin_bit_cast(unsigned, x);
  u += 0x7fffu + ((u >> 16) & 1u);   // RNE, fine for finite values
  return (short)(u >> 16);
}
__device__ __forceinline__ float bf2f(short s) {
  unsigned u = ((unsigned)(unsigned short)s) << 16;
  return __builtin_bit_cast(float, u);
}

// async global -> LDS, 16 B per lane; lds dest is wave-uniform base + lane*16
__device__ __forceinline__ void async_copy16(const void* g, void* l) {
  __builtin_amdgcn_global_load_lds((const __attribute__((address_space(1))) void*)g,
                                   (__attribute__((address_space(3))) void*)l, 16, 0, 0);
}

// ---------------------------------------------------------------------------
// Fused fp32 -> bf16 cast of all 5 tensors in ONE launch.
//   blocks: Wq [0,16384) | Wk [16384,20480) | Wv [20480,24576)
//           | Wo [24576,40960) | hidden [40960,49152)
// ---------------------------------------------------------------------------
__global__ __launch_bounds__(256) void cast_fused(const float* __restrict__ wq,
                                                  const float* __restrict__ wk,
                                                  const float* __restrict__ wv,
                                                  const float* __restrict__ wo,
                                                  const float* __restrict__ hid,
                                                  short* __restrict__ dst) {
  int b = blockIdx.x;
  const float* src;
  int rbase, lblk;
  if (b < 16384)      { src = wq;  rbase = 0;     lblk = b; }
  else if (b < 20480) { src = wk;  rbase = 16384; lblk = b - 16384; }
  else if (b < 24576) { src = wv;  rbase = 20480; lblk = b - 20480; }
  else if (b < 40960) { src = wo;  rbase = 24576; lblk = b - 24576; }
  else                { src = hid; rbase = 40960; lblk = b - 40960; }
  size_t li = (size_t)lblk * 1024 + threadIdx.x * 4;
  float4v v = *(const float4v*)(src + li);
  short4v o;
  o[0] = f2bf(v[0]); o[1] = f2bf(v[1]); o[2] = f2bf(v[2]); o[3] = f2bf(v[3]);
  *(short4v*)(dst + (size_t)rbase * 1024 + li) = o;
}

__device__ __forceinline__ void store_out(float* C, size_t idx, float v) { C[idx] = v; }
__device__ __forceinline__ void store_out(short* C, size_t idx, float v) { C[idx] = f2bf(v); }

// ---------------------------------------------------------------------------
// 256 x (NI*64) THICK 2-phase NT bf16 GEMM (T2 swizzle + counted vmcnt + T5).
// The R4 / best-total variant (121.9 us @ MfmaUtil 36.8%).  512 threads =
// 8 waves (2M x 4N), wave tile 128 x NI*16, BK=64, LDS double-buffered.
// QKV: NI=3 -> 256x192 tile, grid 8*32 = 256 blocks (1/CU, balanced).
// K-tile = 2 phases of 24 MFMA (mi 0-3, mi 4-7); B frags read once at p0.
// Staging chunks/K-tile: A0..A3 + B0..B2; issue p0: A0,A2,B0,B1 | p1: B2,A1,A3.
// Counted waits: end p0 vmcnt(4) (drains t's A1,A3) [last tile vmcnt(0)];
// end p1 vmcnt(2) (drains the 5 chunks next-p0 reads).  Raw s_barrier only.
// Swizzle both-sides: global chunk ^= (row&7); ds_read ofs ^= ((col&7)<<3).
// ---------------------------------------------------------------------------
template <int NI, typename OUT>
__global__ __launch_bounds__(512, 2) void gemm256t(const short* __restrict__ A,
                                                   const short* __restrict__ B,
                                                   OUT* __restrict__ C,
                                                   int M, int N, int K) {
  constexpr int BN = NI * 64;
  __shared__ __align__(16) short As[2][256 * 64];   // 64 KB
  __shared__ __align__(16) short Bs[2][BN * 64];    // 48 KB (NI=3)
  const int tid = threadIdx.x;
  const int lane = tid & 63, w = tid >> 6;
  const int col = lane & 15, quad = lane >> 4;
  const int wm = w >> 2, wn = w & 3;

  // XCD-aware bijective swizzle (nwg = 256, % 8 == 0)
  const int nbx = N / BN;
  int bid = blockIdx.x, nwg = gridDim.x;
  int swz = (nwg & 7) ? bid : ((bid & 7) * (nwg >> 3) + (bid >> 3));
  const int m0 = (swz / nbx) << 8;
  const int n0 = (swz % nbx) * BN;

  // staging source (swizzle folded into the GLOBAL chunk index; LDS linear)
  const int srow = tid >> 3;                       // row within 64-row chunk
  const int schunk = (tid & 7) ^ (srow & 7);       // source 16B-chunk within row
  const short* pA = A + (size_t)(m0 + srow) * K + schunk * 8;
  const short* pB = B + (size_t)(n0 + srow) * K + schunk * 8;
  const int ldst = tid * 8;                        // linear LDS dest (shorts)

  // fragment-read constants: offset = row*64 + ((ks*32 + quad*8) ^ ((row&7)<<3))
  const int sw = (col & 7) << 3;
  const int kof0 = (quad * 8) ^ sw;
  const int kof1 = (32 + quad * 8) ^ sw;
  const int ra = wm * 128, rb = wn * (NI * 16);

  float4v acc[8][NI] = {};
  const int iters = K >> 6;

#define SA(buf, rA, kt) async_copy16(pA + (size_t)(rA) * K + (kt), &As[buf][(rA) * 64 + ldst])
#define SB_(buf, rB, kt) async_copy16(pB + (size_t)(rB) * K + (kt), &Bs[buf][(rB) * 64 + ldst])

  // prologue: tile 0, issue order A0,A2,B0,B1,(B2),A1,A3
  SA(0, 0, 0);  SA(0, 128, 0);
  SB_(0, 0, 0); SB_(0, 64, 0);
  if constexpr (NI == 3) SB_(0, 128, 0);
  SA(0, 64, 0); SA(0, 192, 0);
  asm volatile("s_waitcnt vmcnt(2)" ::: "memory");   // all but A1,A3 resident
  __builtin_amdgcn_s_barrier();

  for (int t = 0; t < iters; ++t) {
    const int cb = t & 1, nb = cb ^ 1;
    const int kt = (t + 1) << 6;
    const bool pf = (t + 1 < iters);
    const short* a_ = As[cb];
    const short* b_ = Bs[cb];
    short8 bf[NI][2];   // held across both phases
    short8 af[4][2];

    // ---- phase 0: mi {0..3}  (+ load all B fragments) ----
#pragma unroll
    for (int j = 0; j < 4; ++j) {
      const short* rp = a_ + (ra + j * 16 + col) * 64;
      af[j][0] = *(const short8*)(rp + kof0);
      af[j][1] = *(const short8*)(rp + kof1);
    }
#pragma unroll
    for (int ni = 0; ni < NI; ++ni) {
      const short* rp = b_ + (rb + ni * 16 + col) * 64;
      bf[ni][0] = *(const short8*)(rp + kof0);
      bf[ni][1] = *(const short8*)(rp + kof1);
    }
    if (pf) { SA(nb, 0, kt); SA(nb, 128, kt); SB_(nb, 0, kt); SB_(nb, 64, kt); }
    __builtin_amdgcn_s_barrier();
    asm volatile("s_waitcnt lgkmcnt(0)" ::: "memory");
    __builtin_amdgcn_sched_barrier(0);
    __builtin_amdgcn_s_setprio(1);
#pragma unroll
    for (int j = 0; j < 4; ++j)
#pragma unroll
      for (int ni = 0; ni < NI; ++ni) {
        acc[j][ni] = MFMA16(af[j][0], bf[ni][0], acc[j][ni]);
        acc[j][ni] = MFMA16(af[j][1], bf[ni][1], acc[j][ni]);
      }
    __builtin_amdgcn_s_setprio(0);
    if (pf) asm volatile("s_waitcnt vmcnt(4)" ::: "memory");  // t's A1,A3 done
    else    asm volatile("s_waitcnt vmcnt(0)" ::: "memory");  // final drain
    __builtin_amdgcn_s_barrier();

    // ---- phase 1: mi {4..7}  (rows in chunks A1/A3) ----
#pragma unroll
    for (int j = 0; j < 4; ++j) {
      const short* rp = a_ + (ra + (4 + j) * 16 + col) * 64;
      af[j][0] = *(const short8*)(rp + kof0);
      af[j][1] = *(const short8*)(rp + kof1);
    }
    if (pf) {
      if constexpr (NI == 3) SB_(nb, 128, kt);
      SA(nb, 64, kt); SA(nb, 192, kt);
    }
    __builtin_amdgcn_s_barrier();
    asm volatile("s_waitcnt lgkmcnt(0)" ::: "memory");
    __builtin_amdgcn_sched_barrier(0);
    __builtin_amdgcn_s_setprio(1);
#pragma unroll
    for (int j = 0; j < 4; ++j)
#pragma unroll
      for (int ni = 0; ni < NI; ++ni) {
        acc[4 + j][ni] = MFMA16(af[j][0], bf[ni][0], acc[4 + j][ni]);
        acc[4 + j][ni] = MFMA16(af[j][1], bf[ni][1], acc[4 + j][ni]);
      }
    __builtin_amdgcn_s_setprio(0);
    if (pf) asm volatile("s_waitcnt vmcnt(2)" ::: "memory");  // t+1 p0 set ready
    __builtin_amdgcn_s_barrier();
  }
#undef SA
#undef SB_

  // epilogue: verified C-layout (row = quad*4+r within fragment, col = lane&15)
#pragma unroll
  for (int mi = 0; mi < 8; ++mi)
#pragma unroll
    for (int ni = 0; ni < NI; ++ni)
#pragma unroll
      for (int r = 0; r < 4; ++r) {
        int row = m0 + ra + mi * 16 + quad * 4 + r;
        int cc  = n0 + rb + ni * 16 + col;
        store_out(C, (size_t)row * N + cc, acc[mi][ni][r]);
      }
}

// ---------------------------------------------------------------------------
// NT bf16 GEMM, double-buffered LDS pipeline: C[M,N] = A[M,K] * B[N,K]^T
// 128x128 tile, BK=32, 256 threads.  Proven for the Wo projection.
// ---------------------------------------------------------------------------
#define BM 128
#define BN 128
#define BK 32

template <typename OUT>
__global__ __launch_bounds__(256) void gemm_nt(const short* __restrict__ A,
                                               const short* __restrict__ B,
                                               OUT* __restrict__ C,
                                               int M, int N, int K) {
  __shared__ __align__(16) short As[2][BM * BK];   // 2 x 8 KB
  __shared__ __align__(16) short Bs[2][BN * BK];   // 2 x 8 KB
  int t = threadIdx.x;
  int w = t >> 6, lane = t & 63;
  int col = lane & 15, quad = lane >> 4;
  int m0 = blockIdx.y * BM, n0 = blockIdx.x * BN;
  int wr = (w >> 1) * 64, wc = (w & 1) * 64;

  int srow   = lane >> 2;
  int schunk = (lane & 3) ^ ((lane >> 3) & 3);
  const short* Ag0 = A + (size_t)(m0 + w * 32 + srow) * K + schunk * 8;
  const short* Ag1 = Ag0 + (size_t)16 * K;
  const short* Bg0 = B + (size_t)(n0 + w * 32 + srow) * K + schunk * 8;
  const short* Bg1 = Bg0 + (size_t)16 * K;
  const int wofs0 = (w * 32) * BK;
  const int wofs1 = (w * 32 + 16) * BK;

  int aswz = (quad ^ ((col >> 1) & 3)) * 8;

  float4v acc[4][4] = {};

  async_copy16(Ag0, &As[0][wofs0]);
  async_copy16(Ag1, &As[0][wofs1]);
  async_copy16(Bg0, &Bs[0][wofs0]);
  async_copy16(Bg1, &Bs[0][wofs1]);
  __syncthreads();

  const int iters = K / BK;
  for (int it = 0; it < iters; it++) {
    const int cb = it & 1, nb = cb ^ 1;
    if (it + 1 < iters) {
      const int k0 = (it + 1) * BK;
      async_copy16(Ag0 + k0, &As[nb][wofs0]);
      async_copy16(Ag1 + k0, &As[nb][wofs1]);
      async_copy16(Bg0 + k0, &Bs[nb][wofs0]);
      async_copy16(Bg1 + k0, &Bs[nb][wofs1]);
    }
    short8 af[4], bfr[4];
#pragma unroll
    for (int i = 0; i < 4; i++)
      af[i] = *(const short8*)&As[cb][(wr + i * 16 + col) * BK + aswz];
#pragma unroll
    for (int i = 0; i < 4; i++)
      bfr[i] = *(const short8*)&Bs[cb][(wc + i * 16 + col) * BK + aswz];
#pragma unroll
    for (int mi = 0; mi < 4; mi++)
#pragma unroll
      for (int ni = 0; ni < 4; ni++)
        acc[mi][ni] = MFMA16(af[mi], bfr[ni], acc[mi][ni]);
    __syncthreads();
  }

#pragma unroll
  for (int mi = 0; mi < 4; mi++)
#pragma unroll
    for (int ni = 0; ni < 4; ni++)
#pragma unroll
      for (int r = 0; r < 4; r++) {
        int row = m0 + wr + mi * 16 + quad * 4 + r;
        int cc  = n0 + wc + ni * 16 + col;
        store_out(C, (size_t)row * N + cc, acc[mi][ni][r]);
      }
}

// ---------------------------------------------------------------------------
// rope_fused: RoPE(Q), RoPE(K), and V-transpose in ONE vectorized launch.
// (Measured win vs scalar rope_kernel + vtrans in R7.)
// ---------------------------------------------------------------------------
__global__ __launch_bounds__(256) void rope_fused(const short* __restrict__ qkv,
                                                  const float* __restrict__ cosp,
                                                  const float* __restrict__ sinp,
                                                  short* __restrict__ qb,
                                                  short* __restrict__ kb,
                                                  short* __restrict__ vt) {
  __shared__ short tile[32][137];
  const int b = blockIdx.x, t = threadIdx.x;

  if (b < 2560) {   // ---- Q / K RoPE ----
    const bool isq = b < 2048;
    const int bb = isq ? b : b - 2048;
    const int head = bb >> 6;
    const int s = ((bb & 63) << 5) + (t >> 3);
    const int d0 = (t & 7) * 8;
    const int cbase = s * HD + d0;
    float4v c0 = *(const float4v*)(cosp + cbase);
    float4v c1 = *(const float4v*)(cosp + cbase + 4);
    float4v s0v = *(const float4v*)(sinp + cbase);
    float4v s1v = *(const float4v*)(sinp + cbase + 4);
    const short* base = qkv + (size_t)s * QKVN + (isq ? head * HD : MODEL + head * HD) + d0;
    short8 lo = *(const short8*)(base);
    short8 hi = *(const short8*)(base + 64);
    const float scale = isq ? 0.08838834764831845f : 1.0f;
    short8 olo, ohi;
#pragma unroll
    for (int j = 0; j < 8; j++) {
      float c = (j < 4) ? c0[j] : c1[j - 4];
      float sn = (j < 4) ? s0v[j] : s1v[j - 4];
      float l = bf2f(lo[j]), h = bf2f(hi[j]);
      olo[j] = f2bf((l * c - h * sn) * scale);
      ohi[j] = f2bf((h * c + l * sn) * scale);
    }
    short* out = (isq ? qb : kb) + ((size_t)(head * SEQ + s)) * HD + d0;
    *(short8*)(out) = olo;
    *(short8*)(out + 64) = ohi;
  } else {          // ---- V transpose ----
    const int bb = b - 2560;
    const int kv = bb >> 6;
    const int s0 = (bb & 63) << 5;
    const int lrow = t >> 4, chunk = t & 15;          // 16 rows x 16 chunks
    const short* src = qkv + (size_t)(s0 + lrow) * QKVN + MODEL + KVDIM + kv * HD + chunk * 8;
#pragma unroll
    for (int rr = 0; rr < 2; rr++)
      *(short8*)&tile[lrow + rr * 16][chunk * 8] =
          *(const short8*)(src + (size_t)rr * 16 * QKVN);
    __syncthreads();
    const int sc = t & 3, d = t >> 2;                 // 4 s-chunks x 64 d
#pragma unroll
    for (int dd = 0; dd < 2; dd++) {
      short8 o;
#pragma unroll
      for (int j = 0; j < 8; j++) o[j] = tile[sc * 8 + j][d + dd * 64];
      *(short8*)(vt + ((size_t)(kv * HD + d + dd * 64)) * SEQ + s0 + sc * 8) = o;
    }
  }
}

// ---------------------------------------------------------------------------
// Flash attention v4 + full-tile fast path: tiles with key0+31 <= q0w cannot
// have any masked element (qrow >= q0w) -> skip the 16 compares/selects.
// Exactly one diagonal tile per wave takes the masked path.  Identical math.
// ---------------------------------------------------------------------------
#define FKT 32    // keys per tile
#define KLD 136   // K LDS stride in shorts (128 + 8 pad)
#define VLD 40    // V LDS stride in shorts (32 + 8 pad)
#define PLD 40    // P LDS stride in shorts

__global__ __launch_bounds__(256, 3) void flash_attn(const short* __restrict__ qb_,
                                                     const short* __restrict__ kb,
                                                     const short* __restrict__ vt,
                                                     short* __restrict__ attn) {
  __shared__ __align__(16) short Ks[2][FKT * KLD];   // 17408 B
  __shared__ __align__(16) short Vs[2][HD * VLD];    // 20480 B
  __shared__ __align__(16) short Ps[4][32 * PLD];    // 10240 B
  const int tid = threadIdx.x;
  const int w = tid >> 6, lane = tid & 63;
  const int col = lane & 15, quad = lane >> 4;
  const int h = blockIdx.x;
  const int kv = h >> 2;
  const int yp = (blockIdx.y < 8) ? (15 - (int)blockIdx.y) : ((int)blockIdx.y - 8);
  const int qB0 = yp * 128;                  // long blocks dispatch first
  const int q0w = qB0 + w * 32;
  const int ntiles = qB0 / FKT + 4;

  short8 ones;
#pragma unroll
  for (int i = 0; i < 8; i++) ones[i] = (short)0x3F80;   // bf16 1.0

  // Q fragments (B-operand): 32 rows x 128 d, pre-scaled by 1/sqrt(D)
  short8 qf[2][4];
  const short* qbase = qb_ + ((size_t)(h * SEQ + q0w + col)) * HD;
#pragma unroll
  for (int rt = 0; rt < 2; rt++)
#pragma unroll
    for (int ks = 0; ks < 4; ks++)
      qf[rt][ks] = *(const short8*)(qbase + rt * 16 * HD + ks * 32 + quad * 8);

  float4v o[2][8] = {};   // O^T: [rt][nc], lane holds d=nc*16+quad*4+r, qrow=rt*16+col
  float4v la[2] = {};     // l[qrow=col] via ones-MFMA (all 4 regs equal)

  // staging geometry
  const int kg_off = tid * 8;
  const int klds0  = (kg_off >> 7) * KLD + (kg_off & 127);
  const int vd     = tid >> 2;
  const int vkof   = (tid & 3) * 8;
  const size_t vrow0 = ((size_t)(kv * HD + vd)) * SEQ;
  const size_t vrow1 = ((size_t)(kv * HD + vd + 64)) * SEQ;
  const int vlds0 = vd * VLD + vkof;
  const short* kgbase = kb + ((size_t)kv * SEQ) * HD;

  short8 kr0, kr1, vr0, vr1;
  kr0 = *(const short8*)(kgbase + kg_off);
  kr1 = *(const short8*)(kgbase + 2048 + kg_off);
  vr0 = *(const short8*)(vt + vrow0 + vkof);
  vr1 = *(const short8*)(vt + vrow1 + vkof);
  *(short8*)&Ks[0][klds0]            = kr0;
  *(short8*)&Ks[0][klds0 + 16 * KLD] = kr1;
  *(short8*)&Vs[0][vlds0]            = vr0;
  *(short8*)&Vs[0][vlds0 + 64 * VLD] = vr1;
  __syncthreads();

  for (int kt = 0; kt < ntiles; kt++) {
    const int b = kt & 1;
    const int key0 = kt * FKT;
    if (kt + 1 < ntiles) {
      const int nk0 = key0 + FKT;
      const short* kg = kgbase + (size_t)nk0 * HD;
      kr0 = *(const short8*)(kg + kg_off);
      kr1 = *(const short8*)(kg + 2048 + kg_off);
      vr0 = *(const short8*)(vt + vrow0 + nk0 + vkof);
      vr1 = *(const short8*)(vt + vrow1 + nk0 + vkof);
    }
    if (key0 <= q0w + 31) {
      // --- S^T = K.Q^T : [kt2][rt], keys kt2*16+quad*4+r, qrow rt*16+col ---
      float4v sct[2][2] = {};
#pragma unroll
      for (int ks = 0; ks < 4; ks++) {
        short8 kf0 = *(const short8*)&Ks[b][col * KLD + ks * 32 + quad * 8];
        short8 kf1 = *(const short8*)&Ks[b][(16 + col) * KLD + ks * 32 + quad * 8];
        sct[0][0] = MFMA16(kf0, qf[0][ks], sct[0][0]);
        sct[0][1] = MFMA16(kf0, qf[1][ks], sct[0][1]);
        sct[1][0] = MFMA16(kf1, qf[0][ks], sct[1][0]);
        sct[1][1] = MFMA16(kf1, qf[1][ks], sct[1][1]);
      }
      // --- exp + packed b64 store of P^T ---
      short* pw = Ps[w];
      if (key0 + 31 <= q0w) {
        // full tile: provably unmasked (keyb+r <= key0+31 <= q0w <= qrow)
#pragma unroll
        for (int rt = 0; rt < 2; rt++)
#pragma unroll
          for (int kt2 = 0; kt2 < 2; kt2++) {
            short4v p;
#pragma unroll
            for (int r = 0; r < 4; r++) p[r] = f2bf(__expf(sct[kt2][rt][r]));
            *(short4v*)&pw[(rt * 16 + col) * PLD + kt2 * 16 + quad * 4] = p;
          }
      } else {
        // diagonal tile (exactly one per wave): masked path
#pragma unroll
        for (int rt = 0; rt < 2; rt++) {
          int qrow = q0w + rt * 16 + col;
#pragma unroll
          for (int kt2 = 0; kt2 < 2; kt2++) {
            int keyb = key0 + kt2 * 16 + quad * 4;
            short4v p;
#pragma unroll
            for (int r = 0; r < 4; r++) {
              float s = sct[kt2][rt][r];
              if (keyb + r > qrow) s = -INFINITY;
              p[r] = f2bf(__expf(s));
            }
            *(short4v*)&pw[(rt * 16 + col) * PLD + kt2 * 16 + quad * 4] = p;
          }
        }
      }
      asm volatile("s_waitcnt lgkmcnt(0)" ::: "memory");
      // --- P^T B-frags, then O^T += V^T . P^T ;  l += ones . P^T ---
      short8 pf0 = *(const short8*)&pw[col * PLD + quad * 8];
      short8 pf1 = *(const short8*)&pw[(16 + col) * PLD + quad * 8];
      la[0] = MFMA16(ones, pf0, la[0]);
      la[1] = MFMA16(ones, pf1, la[1]);
#pragma unroll
      for (int nc = 0; nc < 8; nc++) {
        short8 vb = *(const short8*)&Vs[b][(nc * 16 + col) * VLD + quad * 8];
        o[0][nc] = MFMA16(vb, pf0, o[0][nc]);
        o[1][nc] = MFMA16(vb, pf1, o[1][nc]);
      }
    }
    if (kt + 1 < ntiles) {
      const int nb = 1 - b;
      *(short8*)&Ks[nb][klds0]            = kr0;
      *(short8*)&Ks[nb][klds0 + 16 * KLD] = kr1;
      *(short8*)&Vs[nb][vlds0]            = vr0;
      *(short8*)&Vs[nb][vlds0 + 64 * VLD] = vr1;
    }
    __syncthreads();
  }

  // epilogue: lane's qrow is fixed (= rt*16+col) -> one reciprocal per rt,
  // 4 consecutive d per packed 8-B store.
#pragma unroll
  for (int rt = 0; rt < 2; rt++) {
    float inv = 1.0f / la[rt][0];
    size_t rowbase = (size_t)(q0w + rt * 16 + col) * MODEL + h * HD + quad * 4;
#pragma unroll
    for (int nc = 0; nc < 8; nc++) {
      short4v ov;
#pragma unroll
      for (int r = 0; r < 4; r++) ov[r] = f2bf(o[rt][nc][r] * inv);
      *(short4v*)(attn + rowbase + nc * 16) = ov;
    }
  }
}

// ---------------------------------------------------------------------------
extern "C" void kernel_launch(void* const* d_in, const int* in_sizes, int n_in,
                              void* d_out, int out_size, void* d_ws, size_t ws_size,
                              hipStream_t stream) {
  const float* hidden = (const float*)d_in[0];
  // d_in[1] = attention_mask (pure causal; implemented inline)
  const float* cosp = (const float*)d_in[2];
  const float* sinp = (const float*)d_in[3];
  const float* Wq   = (const float*)d_in[4];
  const float* Wk   = (const float*)d_in[5];
  const float* Wv   = (const float*)d_in[6];
  const float* Wo   = (const float*)d_in[7];

  char* ws = (char*)d_ws;
  size_t off = 0;
  auto alloc = [&](size_t bytes) {
    char* p = ws + off;
    off += (bytes + 255) & ~(size_t)255;
    return p;
  };
  // alloc order wq,wk,wv,wo,h is load-bearing: cast_fused assumes these 5
  // regions are contiguous in this order (all sizes are 256B multiples).
  short* wq_bf = (short*)alloc((size_t)MODEL * MODEL * 2);
  short* wk_bf = (short*)alloc((size_t)KVDIM * MODEL * 2);
  short* wv_bf = (short*)alloc((size_t)KVDIM * MODEL * 2);
  short* wo_bf = (short*)alloc((size_t)MODEL * MODEL * 2);
  short* h_bf  = (short*)alloc((size_t)SEQ * MODEL * 2);
  short* qkv_bf = (short*)alloc((size_t)SEQ * QKVN * 2);
  short* k_bf  = (short*)alloc((size_t)NKV * SEQ * HD * 2);
  short* v_t   = (short*)alloc((size_t)NKV * HD * SEQ * 2);
  short* attn_bf = (short*)alloc((size_t)SEQ * MODEL * 2);
  short* q_bf    = h_bf;             // overlay: h_bf dead after QKV GEMM

  // 1) single fused cast of all 5 fp32 tensors to bf16
  cast_fused<<<49152, 256, 0, stream>>>(Wq, Wk, Wv, Wo, hidden, wq_bf);

  // 2) fused QKV projection: 256x192 thick-2-phase (R4 / best-total variant)
  gemm256t<3, short><<<dim3((SEQ / 256) * (QKVN / 192)), 512, 0, stream>>>(
      h_bf, wq_bf, qkv_bf, SEQ, QKVN, MODEL);

  // 3) RoPE(Q) + RoPE(K) + V-transpose in one vectorized launch
  rope_fused<<<3072, 256, 0, stream>>>(qkv_bf, cosp, sinp, q_bf, k_bf, v_t);

  // 4) flash attention v4 + full-tile fast path
  flash_attn<<<dim3(NH, SEQ / 128), 256, 0, stream>>>(q_bf, k_bf, v_t, attn_bf);

  // 5) output projection straight into d_out (fp32): proven 128^2 kernel
  gemm_nt<float><<<dim3(MODEL / BN, SEQ / BM), 256, 0, stream>>>(
      attn_bf, wo_bf, (float*)d_out, SEQ, MODEL, MODEL);
}

// Round 9
// 470.995 us; speedup vs baseline: 1.2259x; 1.0623x over previous
//
#include <hip/hip_runtime.h>
#include <hip/hip_bf16.h>

// Problem constants
#define SEQ 2048
#define HD  128
#define NH  32
#define NKV 8
#define MODEL 4096   // NH*HD
#define KVDIM 1024   // NKV*HD
#define QKVN 6144    // fused Q+K+V output width

typedef __attribute__((ext_vector_type(8))) short short8;
typedef __attribute__((ext_vector_type(4))) short short4v;
typedef __attribute__((ext_vector_type(4))) float float4v;

#define MFMA16(a, b, c) __builtin_amdgcn_mfma_f32_16x16x32_bf16(a, b, c, 0, 0, 0)

__device__ __forceinline__ short f2bf(float x) {
  unsigned u = __builtin_bit_cast(unsigned, x);
  u += 0x7fffu + ((u >> 16) & 1u);   // RNE, fine for finite values
  return (short)(u >> 16);
}
__device__ __forceinline__ float bf2f(short s) {
  unsigned u = ((unsigned)(unsigned short)s) << 16;
  return __builtin_bit_cast(float, u);
}

// async global -> LDS, 16 B per lane; lds dest is wave-uniform base + lane*16
__device__ __forceinline__ void async_copy16(const void* g, void* l) {
  __builtin_amdgcn_global_load_lds((const __attribute__((address_space(1))) void*)g,
                                   (__attribute__((address_space(3))) void*)l, 16, 0, 0);
}

// ---------------------------------------------------------------------------
// Fused fp32 -> bf16 cast of all 5 tensors in ONE launch.
//   blocks: Wq [0,16384) | Wk [16384,20480) | Wv [20480,24576)
//           | Wo [24576,40960) | hidden [40960,49152)
// ---------------------------------------------------------------------------
__global__ __launch_bounds__(256) void cast_fused(const float* __restrict__ wq,
                                                  const float* __restrict__ wk,
                                                  const float* __restrict__ wv,
                                                  const float* __restrict__ wo,
                                                  const float* __restrict__ hid,
                                                  short* __restrict__ dst) {
  int b = blockIdx.x;
  const float* src;
  int rbase, lblk;
  if (b < 16384)      { src = wq;  rbase = 0;     lblk = b; }
  else if (b < 20480) { src = wk;  rbase = 16384; lblk = b - 16384; }
  else if (b < 24576) { src = wv;  rbase = 20480; lblk = b - 20480; }
  else if (b < 40960) { src = wo;  rbase = 24576; lblk = b - 24576; }
  else                { src = hid; rbase = 40960; lblk = b - 40960; }
  size_t li = (size_t)lblk * 1024 + threadIdx.x * 4;
  float4v v = *(const float4v*)(src + li);
  short4v o;
  o[0] = f2bf(v[0]); o[1] = f2bf(v[1]); o[2] = f2bf(v[2]); o[3] = f2bf(v[3]);
  *(short4v*)(dst + (size_t)rbase * 1024 + li) = o;
}

__device__ __forceinline__ void store_out(float* C, size_t idx, float v) { C[idx] = v; }
__device__ __forceinline__ void store_out(short* C, size_t idx, float v) { C[idx] = f2bf(v); }

// ---------------------------------------------------------------------------
// 256 x (NI*64) THICK 2-phase NT bf16 GEMM (T2 swizzle + counted vmcnt + T5).
// QKV: NI=3 -> 256x192, grid 256 (118 us @ 36.5% MfmaUtil, R8).
// Wo:  NI=2 -> 256x128, grid 256 (NEW this round; 2 phases x 16 MFMA --
//      distinct from R2's failed 4-thin-phase NI=2).
// Wait constants identical for NI=2/3: B2 drops from prologue AND p1
// symmetrically, so end-p0 vmcnt(4) still drains t's {A1,A3} and end-p1
// vmcnt(2) still drains next-p0's first-4 chunks.  Raw s_barrier only.
// Swizzle both-sides: global chunk ^= (row&7); ds_read ofs ^= ((col&7)<<3).
// ---------------------------------------------------------------------------
template <int NI, typename OUT>
__global__ __launch_bounds__(512, 2) void gemm256t(const short* __restrict__ A,
                                                   const short* __restrict__ B,
                                                   OUT* __restrict__ C,
                                                   int M, int N, int K) {
  constexpr int BN = NI * 64;
  __shared__ __align__(16) short As[2][256 * 64];   // 64 KB
  __shared__ __align__(16) short Bs[2][BN * 64];    // 48/32 KB
  const int tid = threadIdx.x;
  const int lane = tid & 63, w = tid >> 6;
  const int col = lane & 15, quad = lane >> 4;
  const int wm = w >> 2, wn = w & 3;

  // XCD-aware bijective swizzle (nwg = 256, % 8 == 0)
  const int nbx = N / BN;
  int bid = blockIdx.x, nwg = gridDim.x;
  int swz = (nwg & 7) ? bid : ((bid & 7) * (nwg >> 3) + (bid >> 3));
  const int m0 = (swz / nbx) << 8;
  const int n0 = (swz % nbx) * BN;

  // staging source (swizzle folded into the GLOBAL chunk index; LDS linear)
  const int srow = tid >> 3;                       // row within 64-row chunk
  const int schunk = (tid & 7) ^ (srow & 7);       // source 16B-chunk within row
  const short* pA = A + (size_t)(m0 + srow) * K + schunk * 8;
  const short* pB = B + (size_t)(n0 + srow) * K + schunk * 8;
  const int ldst = tid * 8;                        // linear LDS dest (shorts)

  // fragment-read constants: offset = row*64 + ((ks*32 + quad*8) ^ ((row&7)<<3))
  const int sw = (col & 7) << 3;
  const int kof0 = (quad * 8) ^ sw;
  const int kof1 = (32 + quad * 8) ^ sw;
  const int ra = wm * 128, rb = wn * (NI * 16);

  float4v acc[8][NI] = {};
  const int iters = K >> 6;

#define SA(buf, rA, kt) async_copy16(pA + (size_t)(rA) * K + (kt), &As[buf][(rA) * 64 + ldst])
#define SB_(buf, rB, kt) async_copy16(pB + (size_t)(rB) * K + (kt), &Bs[buf][(rB) * 64 + ldst])

  // prologue: tile 0, issue order A0,A2,B0,B1,(B2),A1,A3
  SA(0, 0, 0);  SA(0, 128, 0);
  SB_(0, 0, 0); SB_(0, 64, 0);
  if constexpr (NI == 3) SB_(0, 128, 0);
  SA(0, 64, 0); SA(0, 192, 0);
  asm volatile("s_waitcnt vmcnt(2)" ::: "memory");   // all but A1,A3 resident
  __builtin_amdgcn_s_barrier();

  for (int t = 0; t < iters; ++t) {
    const int cb = t & 1, nb = cb ^ 1;
    const int kt = (t + 1) << 6;
    const bool pf = (t + 1 < iters);
    const short* a_ = As[cb];
    const short* b_ = Bs[cb];
    short8 bf[NI][2];   // held across both phases
    short8 af[4][2];

    // ---- phase 0: mi {0..3}  (+ load all B fragments) ----
#pragma unroll
    for (int j = 0; j < 4; ++j) {
      const short* rp = a_ + (ra + j * 16 + col) * 64;
      af[j][0] = *(const short8*)(rp + kof0);
      af[j][1] = *(const short8*)(rp + kof1);
    }
#pragma unroll
    for (int ni = 0; ni < NI; ++ni) {
      const short* rp = b_ + (rb + ni * 16 + col) * 64;
      bf[ni][0] = *(const short8*)(rp + kof0);
      bf[ni][1] = *(const short8*)(rp + kof1);
    }
    if (pf) { SA(nb, 0, kt); SA(nb, 128, kt); SB_(nb, 0, kt); SB_(nb, 64, kt); }
    __builtin_amdgcn_s_barrier();
    asm volatile("s_waitcnt lgkmcnt(0)" ::: "memory");
    __builtin_amdgcn_sched_barrier(0);
    __builtin_amdgcn_s_setprio(1);
#pragma unroll
    for (int j = 0; j < 4; ++j)
#pragma unroll
      for (int ni = 0; ni < NI; ++ni) {
        acc[j][ni] = MFMA16(af[j][0], bf[ni][0], acc[j][ni]);
        acc[j][ni] = MFMA16(af[j][1], bf[ni][1], acc[j][ni]);
      }
    __builtin_amdgcn_s_setprio(0);
    if (pf) asm volatile("s_waitcnt vmcnt(4)" ::: "memory");  // t's A1,A3 done
    else    asm volatile("s_waitcnt vmcnt(0)" ::: "memory");  // final drain
    __builtin_amdgcn_s_barrier();

    // ---- phase 1: mi {4..7}  (rows in chunks A1/A3) ----
#pragma unroll
    for (int j = 0; j < 4; ++j) {
      const short* rp = a_ + (ra + (4 + j) * 16 + col) * 64;
      af[j][0] = *(const short8*)(rp + kof0);
      af[j][1] = *(const short8*)(rp + kof1);
    }
    if (pf) {
      if constexpr (NI == 3) SB_(nb, 128, kt);
      SA(nb, 64, kt); SA(nb, 192, kt);
    }
    __builtin_amdgcn_s_barrier();
    asm volatile("s_waitcnt lgkmcnt(0)" ::: "memory");
    __builtin_amdgcn_sched_barrier(0);
    __builtin_amdgcn_s_setprio(1);
#pragma unroll
    for (int j = 0; j < 4; ++j)
#pragma unroll
      for (int ni = 0; ni < NI; ++ni) {
        acc[4 + j][ni] = MFMA16(af[j][0], bf[ni][0], acc[4 + j][ni]);
        acc[4 + j][ni] = MFMA16(af[j][1], bf[ni][1], acc[4 + j][ni]);
      }
    __builtin_amdgcn_s_setprio(0);
    if (pf) asm volatile("s_waitcnt vmcnt(2)" ::: "memory");  // t+1 p0 set ready
    __builtin_amdgcn_s_barrier();
  }
#undef SA
#undef SB_

  // epilogue: verified C-layout (row = quad*4+r within fragment, col = lane&15)
#pragma unroll
  for (int mi = 0; mi < 8; ++mi)
#pragma unroll
    for (int ni = 0; ni < NI; ++ni)
#pragma unroll
      for (int r = 0; r < 4; ++r) {
        int row = m0 + ra + mi * 16 + quad * 4 + r;
        int cc  = n0 + rb + ni * 16 + col;
        store_out(C, (size_t)row * N + cc, acc[mi][ni][r]);
      }
}

// ---------------------------------------------------------------------------
// ropek_vtrans: RoPE(K) + V-transpose (Q-RoPE moved into flash_attn, which
// reads raw Q from qkv_bf -- the rotary d<->d+64 pairing is lane-local there).
// Sections by blockIdx.x (256 threads each):
//   [0,512):    K rope   hk = b>>6,        s0 = (b&63)*32
//   [512,1024): V trans  kv = (b-512)>>6,  s0 = ((b-512)&63)*32
// ---------------------------------------------------------------------------
__global__ __launch_bounds__(256) void ropek_vtrans(const short* __restrict__ qkv,
                                                    const float* __restrict__ cosp,
                                                    const float* __restrict__ sinp,
                                                    short* __restrict__ kb,
                                                    short* __restrict__ vt) {
  __shared__ short tile[32][137];
  const int b = blockIdx.x, t = threadIdx.x;

  if (b < 512) {    // ---- K RoPE ----
    const int head = b >> 6;
    const int s = ((b & 63) << 5) + (t >> 3);
    const int d0 = (t & 7) * 8;
    const int cbase = s * HD + d0;
    float4v c0 = *(const float4v*)(cosp + cbase);
    float4v c1 = *(const float4v*)(cosp + cbase + 4);
    float4v s0v = *(const float4v*)(sinp + cbase);
    float4v s1v = *(const float4v*)(sinp + cbase + 4);
    const short* base = qkv + (size_t)s * QKVN + MODEL + head * HD + d0;
    short8 lo = *(const short8*)(base);
    short8 hi = *(const short8*)(base + 64);
    short8 olo, ohi;
#pragma unroll
    for (int j = 0; j < 8; j++) {
      float c = (j < 4) ? c0[j] : c1[j - 4];
      float sn = (j < 4) ? s0v[j] : s1v[j - 4];
      float l = bf2f(lo[j]), h = bf2f(hi[j]);
      olo[j] = f2bf(l * c - h * sn);
      ohi[j] = f2bf(h * c + l * sn);
    }
    short* out = kb + ((size_t)(head * SEQ + s)) * HD + d0;
    *(short8*)(out) = olo;
    *(short8*)(out + 64) = ohi;
  } else {          // ---- V transpose ----
    const int bb = b - 512;
    const int kv = bb >> 6;
    const int s0 = (bb & 63) << 5;
    const int lrow = t >> 4, chunk = t & 15;          // 16 rows x 16 chunks
    const short* src = qkv + (size_t)(s0 + lrow) * QKVN + MODEL + KVDIM + kv * HD + chunk * 8;
#pragma unroll
    for (int rr = 0; rr < 2; rr++)
      *(short8*)&tile[lrow + rr * 16][chunk * 8] =
          *(const short8*)(src + (size_t)rr * 16 * QKVN);
    __syncthreads();
    const int sc = t & 3, d = t >> 2;                 // 4 s-chunks x 64 d
#pragma unroll
    for (int dd = 0; dd < 2; dd++) {
      short8 o;
#pragma unroll
      for (int j = 0; j < 8; j++) o[j] = tile[sc * 8 + j][d + dd * 64];
      *(short8*)(vt + ((size_t)(kv * HD + d + dd * 64)) * SEQ + s0 + sc * 8) = o;
    }
  }
}

// ---------------------------------------------------------------------------
// Flash attention v4 + inline Q-RoPE.  Q is read RAW from qkv_bf once per
// block; the rotary pairing d <-> d+64 maps to qf[rt][ks] <-> qf[rt][ks+2]
// in the SAME lane (d = ks*32+quad*8+j), so RoPE is pure in-register FMA --
// no shuffles, bit-identical math to the old rope_kernel (same f2bf RNE).
// Eliminates the q_bf write+read round trip (33.6 MB).
// ---------------------------------------------------------------------------
#define FKT 32    // keys per tile
#define KLD 136   // K LDS stride in shorts (128 + 8 pad)
#define VLD 40    // V LDS stride in shorts (32 + 8 pad)
#define PLD 40    // P LDS stride in shorts

__global__ __launch_bounds__(256, 3) void flash_attn(const short* __restrict__ qkv,
                                                     const float* __restrict__ cosp,
                                                     const float* __restrict__ sinp,
                                                     const short* __restrict__ kb,
                                                     const short* __restrict__ vt,
                                                     short* __restrict__ attn) {
  __shared__ __align__(16) short Ks[2][FKT * KLD];   // 17408 B
  __shared__ __align__(16) short Vs[2][HD * VLD];    // 20480 B
  __shared__ __align__(16) short Ps[4][32 * PLD];    // 10240 B
  const int tid = threadIdx.x;
  const int w = tid >> 6, lane = tid & 63;
  const int col = lane & 15, quad = lane >> 4;
  const int h = blockIdx.x;
  const int kv = h >> 2;
  const int yp = (blockIdx.y < 8) ? (15 - (int)blockIdx.y) : ((int)blockIdx.y - 8);
  const int qB0 = yp * 128;                  // long blocks dispatch first
  const int q0w = qB0 + w * 32;
  const int ntiles = qB0 / FKT + 4;

  short8 ones;
#pragma unroll
  for (int i = 0; i < 8; i++) ones[i] = (short)0x3F80;   // bf16 1.0

  // Q fragments (B-operand) with inline RoPE + 1/sqrt(D) pre-scale
  short8 qf[2][4];
  {
    const short* qrow0 = qkv + (size_t)(q0w + col) * QKVN + h * HD;
    const float* cb0 = cosp + (size_t)(q0w + col) * HD;
    const float* sb0 = sinp + (size_t)(q0w + col) * HD;
#pragma unroll
    for (int rt = 0; rt < 2; rt++) {
      const short* qr = qrow0 + (size_t)rt * 16 * QKVN;
      const float* cr = cb0 + rt * 16 * HD;
      const float* sr = sb0 + rt * 16 * HD;
#pragma unroll
      for (int ks = 0; ks < 2; ks++) {
        short8 lo = *(const short8*)(qr + ks * 32 + quad * 8);
        short8 hi = *(const short8*)(qr + 64 + ks * 32 + quad * 8);
        const float* cc = cr + ks * 32 + quad * 8;
        const float* ss = sr + ks * 32 + quad * 8;
        short8 olo, ohi;
#pragma unroll
        for (int j = 0; j < 8; j++) {
          float c = cc[j], sn = ss[j];
          float l = bf2f(lo[j]), hh = bf2f(hi[j]);
          olo[j] = f2bf((l * c - hh * sn) * 0.08838834764831845f);
          ohi[j] = f2bf((hh * c + l * sn) * 0.08838834764831845f);
        }
        qf[rt][ks]     = olo;   // d = ks*32+quad*8 .. +7   (< 64)
        qf[rt][ks + 2] = ohi;   // d + 64
      }
    }
  }

  float4v o[2][8] = {};   // O^T: [rt][nc], lane holds d=nc*16+quad*4+r, qrow=rt*16+col
  float4v la[2] = {};     // l[qrow=col] via ones-MFMA (all 4 regs equal)

  // staging geometry
  const int kg_off = tid * 8;
  const int klds0  = (kg_off >> 7) * KLD + (kg_off & 127);
  const int vd     = tid >> 2;
  const int vkof   = (tid & 3) * 8;
  const size_t vrow0 = ((size_t)(kv * HD + vd)) * SEQ;
  const size_t vrow1 = ((size_t)(kv * HD + vd + 64)) * SEQ;
  const int vlds0 = vd * VLD + vkof;
  const short* kgbase = kb + ((size_t)kv * SEQ) * HD;

  short8 kr0, kr1, vr0, vr1;
  kr0 = *(const short8*)(kgbase + kg_off);
  kr1 = *(const short8*)(kgbase + 2048 + kg_off);
  vr0 = *(const short8*)(vt + vrow0 + vkof);
  vr1 = *(const short8*)(vt + vrow1 + vkof);
  *(short8*)&Ks[0][klds0]            = kr0;
  *(short8*)&Ks[0][klds0 + 16 * KLD] = kr1;
  *(short8*)&Vs[0][vlds0]            = vr0;
  *(short8*)&Vs[0][vlds0 + 64 * VLD] = vr1;
  __syncthreads();

  for (int kt = 0; kt < ntiles; kt++) {
    const int b = kt & 1;
    const int key0 = kt * FKT;
    if (kt + 1 < ntiles) {
      const int nk0 = key0 + FKT;
      const short* kg = kgbase + (size_t)nk0 * HD;
      kr0 = *(const short8*)(kg + kg_off);
      kr1 = *(const short8*)(kg + 2048 + kg_off);
      vr0 = *(const short8*)(vt + vrow0 + nk0 + vkof);
      vr1 = *(const short8*)(vt + vrow1 + nk0 + vkof);
    }
    if (key0 <= q0w + 31) {
      // --- S^T = K.Q^T : [kt2][rt], keys kt2*16+quad*4+r, qrow rt*16+col ---
      float4v sct[2][2] = {};
#pragma unroll
      for (int ks = 0; ks < 4; ks++) {
        short8 kf0 = *(const short8*)&Ks[b][col * KLD + ks * 32 + quad * 8];
        short8 kf1 = *(const short8*)&Ks[b][(16 + col) * KLD + ks * 32 + quad * 8];
        sct[0][0] = MFMA16(kf0, qf[0][ks], sct[0][0]);
        sct[0][1] = MFMA16(kf0, qf[1][ks], sct[0][1]);
        sct[1][0] = MFMA16(kf1, qf[0][ks], sct[1][0]);
        sct[1][1] = MFMA16(kf1, qf[1][ks], sct[1][1]);
      }
      // --- exp + packed b64 store of P^T ---
      short* pw = Ps[w];
      if (key0 + 31 <= q0w) {
        // full tile: provably unmasked (keyb+r <= key0+31 <= q0w <= qrow)
#pragma unroll
        for (int rt = 0; rt < 2; rt++)
#pragma unroll
          for (int kt2 = 0; kt2 < 2; kt2++) {
            short4v p;
#pragma unroll
            for (int r = 0; r < 4; r++) p[r] = f2bf(__expf(sct[kt2][rt][r]));
            *(short4v*)&pw[(rt * 16 + col) * PLD + kt2 * 16 + quad * 4] = p;
          }
      } else {
        // diagonal tile (exactly one per wave): masked path
#pragma unroll
        for (int rt = 0; rt < 2; rt++) {
          int qrow = q0w + rt * 16 + col;
#pragma unroll
          for (int kt2 = 0; kt2 < 2; kt2++) {
            int keyb = key0 + kt2 * 16 + quad * 4;
            short4v p;
#pragma unroll
            for (int r = 0; r < 4; r++) {
              float s = sct[kt2][rt][r];
              if (keyb + r > qrow) s = -INFINITY;
              p[r] = f2bf(__expf(s));
            }
            *(short4v*)&pw[(rt * 16 + col) * PLD + kt2 * 16 + quad * 4] = p;
          }
        }
      }
      asm volatile("s_waitcnt lgkmcnt(0)" ::: "memory");
      // --- P^T B-frags, then O^T += V^T . P^T ;  l += ones . P^T ---
      short8 pf0 = *(const short8*)&pw[col * PLD + quad * 8];
      short8 pf1 = *(const short8*)&pw[(16 + col) * PLD + quad * 8];
      la[0] = MFMA16(ones, pf0, la[0]);
      la[1] = MFMA16(ones, pf1, la[1]);
#pragma unroll
      for (int nc = 0; nc < 8; nc++) {
        short8 vb = *(const short8*)&Vs[b][(nc * 16 + col) * VLD + quad * 8];
        o[0][nc] = MFMA16(vb, pf0, o[0][nc]);
        o[1][nc] = MFMA16(vb, pf1, o[1][nc]);
      }
    }
    if (kt + 1 < ntiles) {
      const int nb = 1 - b;
      *(short8*)&Ks[nb][klds0]            = kr0;
      *(short8*)&Ks[nb][klds0 + 16 * KLD] = kr1;
      *(short8*)&Vs[nb][vlds0]            = vr0;
      *(short8*)&Vs[nb][vlds0 + 64 * VLD] = vr1;
    }
    __syncthreads();
  }

  // epilogue: lane's qrow is fixed (= rt*16+col) -> one reciprocal per rt,
  // 4 consecutive d per packed 8-B store.
#pragma unroll
  for (int rt = 0; rt < 2; rt++) {
    float inv = 1.0f / la[rt][0];
    size_t rowbase = (size_t)(q0w + rt * 16 + col) * MODEL + h * HD + quad * 4;
#pragma unroll
    for (int nc = 0; nc < 8; nc++) {
      short4v ov;
#pragma unroll
      for (int r = 0; r < 4; r++) ov[r] = f2bf(o[rt][nc][r] * inv);
      *(short4v*)(attn + rowbase + nc * 16) = ov;
    }
  }
}

// ---------------------------------------------------------------------------
extern "C" void kernel_launch(void* const* d_in, const int* in_sizes, int n_in,
                              void* d_out, int out_size, void* d_ws, size_t ws_size,
                              hipStream_t stream) {
  const float* hidden = (const float*)d_in[0];
  // d_in[1] = attention_mask (pure causal; implemented inline)
  const float* cosp = (const float*)d_in[2];
  const float* sinp = (const float*)d_in[3];
  const float* Wq   = (const float*)d_in[4];
  const float* Wk   = (const float*)d_in[5];
  const float* Wv   = (const float*)d_in[6];
  const float* Wo   = (const float*)d_in[7];

  char* ws = (char*)d_ws;
  size_t off = 0;
  auto alloc = [&](size_t bytes) {
    char* p = ws + off;
    off += (bytes + 255) & ~(size_t)255;
    return p;
  };
  // alloc order wq,wk,wv,wo,h is load-bearing: cast_fused assumes these 5
  // regions are contiguous in this order (all sizes are 256B multiples).
  short* wq_bf = (short*)alloc((size_t)MODEL * MODEL * 2);
  short* wk_bf = (short*)alloc((size_t)KVDIM * MODEL * 2);
  short* wv_bf = (short*)alloc((size_t)KVDIM * MODEL * 2);
  short* wo_bf = (short*)alloc((size_t)MODEL * MODEL * 2);
  short* h_bf  = (short*)alloc((size_t)SEQ * MODEL * 2);
  short* qkv_bf = (short*)alloc((size_t)SEQ * QKVN * 2);
  short* k_bf  = (short*)alloc((size_t)NKV * SEQ * HD * 2);
  short* v_t   = (short*)alloc((size_t)NKV * HD * SEQ * 2);
  short* attn_bf = (short*)alloc((size_t)SEQ * MODEL * 2);

  // 1) single fused cast of all 5 fp32 tensors to bf16
  cast_fused<<<49152, 256, 0, stream>>>(Wq, Wk, Wv, Wo, hidden, wq_bf);

  // 2) fused QKV projection: 256x192 thick-2-phase (R8-proven, 118 us)
  gemm256t<3, short><<<dim3((SEQ / 256) * (QKVN / 192)), 512, 0, stream>>>(
      h_bf, wq_bf, qkv_bf, SEQ, QKVN, MODEL);

  // 3) RoPE(K) + V-transpose (Q-RoPE is inlined in flash_attn)
  ropek_vtrans<<<1024, 256, 0, stream>>>(qkv_bf, cosp, sinp, k_bf, v_t);

  // 4) flash attention v4 + inline Q-RoPE (reads raw Q from qkv_bf)
  flash_attn<<<dim3(NH, SEQ / 128), 256, 0, stream>>>(qkv_bf, cosp, sinp, k_bf, v_t, attn_bf);

  // 5) output projection: 256x128 thick-2-phase, grid 256 (replaces gemm_nt)
  gemm256t<2, float><<<dim3((SEQ / 256) * (MODEL / 128)), 512, 0, stream>>>(
      attn_bf, wo_bf, (float*)d_out, SEQ, MODEL, MODEL);
}